// Round 1
// baseline (1572.523 us; speedup 1.0000x reference)
//
#include <hip/hip_runtime.h>
#include <math.h>

#define BATCH 8
#define SEQ   1024
#define HID   768
#define HEADS 6
#define DHEAD 64
#define ALLH  384   // HEADS*DHEAD
#define KS    9
#define PADC  4
#define MROWS (BATCH*SEQ)  // 8192

// ---------------- depthwise conv on K: y[b,s,c] = sum_t K[b,s+t-4,c]*dw[c,t] ----------------
__global__ __launch_bounds__(256) void dconv_kernel(const float* __restrict__ Kin,
                                                    const float* __restrict__ dw,
                                                    float* __restrict__ y) {
    int idx = blockIdx.x * 256 + threadIdx.x;
    if (idx >= MROWS * HID) return;
    int c = idx % HID;
    int s = (idx / HID) % SEQ;
    int b = idx / (HID * SEQ);
    float acc = 0.f;
#pragma unroll
    for (int t = 0; t < KS; ++t) {
        int sj = s + t - PADC;
        if (sj >= 0 && sj < SEQ)
            acc += Kin[((size_t)b * SEQ + sj) * HID + c] * dw[c * KS + t];
    }
    y[idx] = acc;
}

// ---------------- generic fp32 tiled GEMM: C[M,N] = A[M,K] @ B (+bias) ----------------
// BT=false: B stored [K,N]. BT=true: B stored [N,K].
template <bool BT, bool HAS_BIAS>
__global__ __launch_bounds__(256) void gemm64_kernel(const float* __restrict__ A,
                                                     const float* __restrict__ B,
                                                     const float* __restrict__ bias,
                                                     float* __restrict__ C,
                                                     int M, int N, int Kd) {
    __shared__ float As[16][68];
    __shared__ float Bs[16][68];
    int m0 = blockIdx.x * 64;
    int n0 = blockIdx.y * 64;
    int tid = threadIdx.x;
    int tx = tid % 16, ty = tid / 16;
    float acc[4][4] = {};
    for (int k0 = 0; k0 < Kd; k0 += 16) {
#pragma unroll
        for (int i = 0; i < 4; ++i) {
            int e = tid + i * 256;
            int kk = e % 16, m = e / 16;
            As[kk][m] = A[(size_t)(m0 + m) * Kd + k0 + kk];
        }
#pragma unroll
        for (int i = 0; i < 4; ++i) {
            int e = tid + i * 256;
            if (BT) {
                int kk = e % 16, n = e / 16;
                Bs[kk][n] = B[(size_t)(n0 + n) * Kd + k0 + kk];
            } else {
                int n = e % 64, kk = e / 64;
                Bs[kk][n] = B[(size_t)(k0 + kk) * N + n0 + n];
            }
        }
        __syncthreads();
#pragma unroll
        for (int kk = 0; kk < 16; ++kk) {
            float a[4], bv[4];
#pragma unroll
            for (int i = 0; i < 4; ++i) a[i] = As[kk][ty * 4 + i];
#pragma unroll
            for (int j = 0; j < 4; ++j) bv[j] = Bs[kk][tx * 4 + j];
#pragma unroll
            for (int i = 0; i < 4; ++i)
#pragma unroll
                for (int j = 0; j < 4; ++j) acc[i][j] += a[i] * bv[j];
        }
        __syncthreads();
    }
#pragma unroll
    for (int i = 0; i < 4; ++i) {
        int m = m0 + ty * 4 + i;
#pragma unroll
        for (int j = 0; j < 4; ++j) {
            int n = n0 + tx * 4 + j;
            float v = acc[i][j];
            if (HAS_BIAS) v += bias[n];
            C[(size_t)m * N + n] = v;
        }
    }
}

// ---------------- span kernel: kern = softmax((keyconv*q) @ Wck + bck) over 9 taps ----------------
__global__ __launch_bounds__(256) void spankern_kernel(const float* __restrict__ keyconv,
                                                       const float* __restrict__ q,
                                                       const float* __restrict__ Wck,
                                                       const float* __restrict__ bck,
                                                       float* __restrict__ kern_sm) {
    __shared__ float ca[4][ALLH];
    __shared__ float kv[4][64];
    int row0 = blockIdx.x * 4;
    int tid = threadIdx.x;
    int r = tid >> 6;
    int lane = tid & 63;
    int row = row0 + r;
    for (int e = lane; e < ALLH; e += 64) {
        size_t off = (size_t)row * ALLH + e;
        ca[r][e] = keyconv[off] * q[off];
    }
    __syncthreads();
    float val = 0.f;
    if (lane < HEADS * KS) {
        for (int kidx = 0; kidx < ALLH; ++kidx)
            val += ca[r][kidx] * Wck[kidx * (HEADS * KS) + lane];
        val += bck[lane];
    }
    kv[r][lane] = val;
    __syncthreads();
    if (lane < HEADS) {
        float mx = -INFINITY;
#pragma unroll
        for (int t = 0; t < KS; ++t) mx = fmaxf(mx, kv[r][lane * KS + t]);
        float e[KS];
        float sum = 0.f;
#pragma unroll
        for (int t = 0; t < KS; ++t) {
            e[t] = expf(kv[r][lane * KS + t] - mx);
            sum += e[t];
        }
        float inv = 1.f / sum;
#pragma unroll
        for (int t = 0; t < KS; ++t)
            kern_sm[((size_t)row * HEADS + lane) * KS + t] = e[t] * inv;
    }
}

// ---------------- conv_out: out[b,s,384+c] = sum_t co[b,s+t-4,c] * kern[b,s,c/64,t] ----------------
__global__ __launch_bounds__(256) void convout_kernel(const float* __restrict__ co,
                                                      const float* __restrict__ kern_sm,
                                                      float* __restrict__ out) {
    int idx = blockIdx.x * 256 + threadIdx.x;
    if (idx >= MROWS * ALLH) return;
    int c = idx % ALLH;
    int s = (idx / ALLH) % SEQ;
    int b = idx / (ALLH * SEQ);
    int h = c / DHEAD;
    const float* ks = &kern_sm[(((size_t)b * SEQ + s) * HEADS + h) * KS];
    float acc = 0.f;
#pragma unroll
    for (int t = 0; t < KS; ++t) {
        int sj = s + t - PADC;
        if (sj >= 0 && sj < SEQ)
            acc += co[((size_t)b * SEQ + sj) * ALLH + c] * ks[t];
    }
    out[((size_t)b * SEQ + s) * (2 * ALLH) + ALLH + c] = acc;
}

// ---------------- fused monotonic attention ----------------
// block = 256 threads, handles ROWS=8 query rows of one (b,h).
#define ROWS 8
__global__ __launch_bounds__(256) void attn_kernel(const float* __restrict__ q,
                                                   const float* __restrict__ k,
                                                   const float* __restrict__ v,
                                                   const int* __restrict__ mask,
                                                   const float* __restrict__ gammas,
                                                   float* __restrict__ out) {
    __shared__ float s_sc[ROWS][SEQ];        // 32 KB scores -> scores2 -> e2
    __shared__ float q_s[ROWS][DHEAD];       // 2 KB
    __shared__ float tile[64][DHEAD + 1];    // 16.25 KB k/v staging
    __shared__ float s_msk[SEQ];             // 4 KB
    __shared__ float rstat[ROWS];

    int blk = blockIdx.x;
    int i0 = (blk % (SEQ / ROWS)) * ROWS;
    int h = (blk / (SEQ / ROWS)) % HEADS;
    int b = blk / ((SEQ / ROWS) * HEADS);
    int tid = threadIdx.x;

    float gamma = -log1pf(expf(gammas[h]));  // -softplus(gammas[h])

    // stage q rows + mask
    for (int e = tid; e < ROWS * DHEAD; e += 256) {
        int r = e / DHEAD, d = e % DHEAD;
        q_s[r][d] = q[((size_t)b * SEQ + i0 + r) * ALLH + h * DHEAD + d];
    }
    for (int e = tid; e < SEQ; e += 256)
        s_msk[e] = (mask[b * SEQ + e] != 0) ? 1.f : 0.f;
    __syncthreads();

    const float scale = 0.125f;  // 1/sqrt(64)
    int jj = tid & 63;
    int r0 = tid >> 6;  // wave-uniform: 0..3

    // ---- scores ----
    for (int j0 = 0; j0 < SEQ; j0 += 64) {
        for (int e = tid; e < 64 * 16; e += 256) {
            int jr = e >> 4, d4 = e & 15;
            const float4 val = *reinterpret_cast<const float4*>(
                &k[((size_t)b * SEQ + j0 + jr) * ALLH + h * DHEAD + d4 * 4]);
            tile[jr][d4 * 4 + 0] = val.x;
            tile[jr][d4 * 4 + 1] = val.y;
            tile[jr][d4 * 4 + 2] = val.z;
            tile[jr][d4 * 4 + 3] = val.w;
        }
        __syncthreads();
        float acc0 = 0.f, acc1 = 0.f;
#pragma unroll
        for (int d = 0; d < DHEAD; ++d) {
            float kv = tile[jj][d];
            acc0 += q_s[r0][d] * kv;
            acc1 += q_s[r0 + 4][d] * kv;
        }
        s_sc[r0][j0 + jj] = acc0 * scale;
        s_sc[r0 + 4][j0 + jj] = acc1 * scale;
        __syncthreads();
    }

    // ---- softmax + monotonic distance modulation (32 threads per row) ----
    {
        int r = tid >> 5;   // 0..7
        int t = tid & 31;   // lane in group
        int i = i0 + r;

        // row max (masked)
        float mx = -INFINITY;
        for (int c = 0; c < 32; ++c) {
            int j = t + c * 32;
            float sv = (s_msk[j] != 0.f) ? s_sc[r][j] : -INFINITY;
            mx = fmaxf(mx, sv);
        }
#pragma unroll
        for (int off = 16; off; off >>= 1) mx = fmaxf(mx, __shfl_xor(mx, off, 32));

        // chunk exp-sums (chunk = contiguous 32 elements per lane)
        float csum = 0.f;
        for (int c = 0; c < 32; ++c) {
            int j = t * 32 + c;
            if (s_msk[j] != 0.f) csum += expf(s_sc[r][j] - mx);
        }
        // inclusive scan across 32 lanes
        float incl = csum;
#pragma unroll
        for (int off = 1; off < 32; off <<= 1) {
            float nb = __shfl_up(incl, off, 32);
            if (t >= off) incl += nb;
        }
        float tot = __shfl(incl, 31, 32);
        float excl = incl - csum;
        float inv_tot = 1.0f / tot;

        // per-element: cum, dist, effect, scores2 (overwrite s_sc); track new max
        float run = 0.f, m2 = -INFINITY;
        for (int c = 0; c < 32; ++c) {
            int j = t * 32 + c;
            float sv = s_sc[r][j];
            bool um = (s_msk[j] != 0.f);
            float e = um ? expf(sv - mx) : 0.f;
            run += e;
            float rem = (tot - (excl + run)) * inv_tot;  // (tot - cum) normalized
            float pos = fabsf((float)(i - j));
            float dist = sqrtf(fmaxf(rem * pos, 0.f));
            float eff = fminf(fmaxf(expf(dist * gamma), 1e-5f), 1e5f);
            float s2 = um ? sv * eff : -1e8f;
            s_sc[r][j] = s2;
            m2 = fmaxf(m2, s2);
        }
#pragma unroll
        for (int off = 16; off; off >>= 1) m2 = fmaxf(m2, __shfl_xor(m2, off, 32));

        // second softmax: store e2 in place, sum
        float sum2 = 0.f;
        for (int c = 0; c < 32; ++c) {
            int j = t + c * 32;
            float e2 = expf(s_sc[r][j] - m2);
            s_sc[r][j] = e2;
            sum2 += e2;
        }
#pragma unroll
        for (int off = 16; off; off >>= 1) sum2 += __shfl_xor(sum2, off, 32);
        if (t == 0) rstat[r] = 1.0f / sum2;
    }
    __syncthreads();

    // ---- PV ----
    int d = tid & 63;
    float acc0 = 0.f, acc1 = 0.f;
    for (int j0 = 0; j0 < SEQ; j0 += 64) {
        for (int e = tid; e < 64 * 16; e += 256) {
            int jr = e >> 4, d4 = e & 15;
            const float4 val = *reinterpret_cast<const float4*>(
                &v[((size_t)b * SEQ + j0 + jr) * ALLH + h * DHEAD + d4 * 4]);
            tile[jr][d4 * 4 + 0] = val.x;
            tile[jr][d4 * 4 + 1] = val.y;
            tile[jr][d4 * 4 + 2] = val.z;
            tile[jr][d4 * 4 + 3] = val.w;
        }
        __syncthreads();
#pragma unroll 8
        for (int jr = 0; jr < 64; ++jr) {
            float vv = tile[jr][d];
            acc0 += s_sc[r0][j0 + jr] * vv;
            acc1 += s_sc[r0 + 4][j0 + jr] * vv;
        }
        __syncthreads();
    }
    out[((size_t)b * SEQ + i0 + r0) * (2 * ALLH) + h * DHEAD + d] = acc0 * rstat[r0];
    out[((size_t)b * SEQ + i0 + r0 + 4) * (2 * ALLH) + h * DHEAD + d] = acc1 * rstat[r0 + 4];
}

// ---------------- launch ----------------
extern "C" void kernel_launch(void* const* d_in, const int* in_sizes, int n_in,
                              void* d_out, int out_size, void* d_ws, size_t ws_size,
                              hipStream_t stream) {
    const float* Q = (const float*)d_in[0];
    const float* Kin = (const float*)d_in[1];
    const float* V = (const float*)d_in[2];
    const float* Wq = (const float*)d_in[3];
    const float* Wk = (const float*)d_in[4];
    const float* Wv = (const float*)d_in[5];
    const float* dw = (const float*)d_in[6];
    const float* pw = (const float*)d_in[7];
    const float* sep_bias = (const float*)d_in[8];
    const float* Wck = (const float*)d_in[9];
    const float* bck = (const float*)d_in[10];
    const float* Wco = (const float*)d_in[11];
    const float* bco = (const float*)d_in[12];
    const float* gammas = (const float*)d_in[13];
    const int* mask = (const int*)d_in[14];
    float* out = (float*)d_out;
    float* ws = (float*)d_ws;

    float* qb  = ws;                    // 8192*384
    float* kb  = qb + (size_t)MROWS * ALLH;
    float* vb  = kb + (size_t)MROWS * ALLH;
    float* cob = vb + (size_t)MROWS * ALLH;
    float* kcb = cob + (size_t)MROWS * ALLH;
    float* yb  = kcb + (size_t)MROWS * ALLH;   // 8192*768
    float* kern = yb + (size_t)MROWS * HID;    // 8192*54

    // 1. depthwise conv on K
    dconv_kernel<<<(MROWS * HID + 255) / 256, 256, 0, stream>>>(Kin, dw, yb);

    // 2. projection GEMMs
    dim3 g(MROWS / 64, ALLH / 64);
    gemm64_kernel<false, false><<<g, 256, 0, stream>>>(Q, Wq, nullptr, qb, MROWS, ALLH, HID);
    gemm64_kernel<false, false><<<g, 256, 0, stream>>>(Kin, Wk, nullptr, kb, MROWS, ALLH, HID);
    gemm64_kernel<false, false><<<g, 256, 0, stream>>>(V, Wv, nullptr, vb, MROWS, ALLH, HID);
    gemm64_kernel<false, true><<<g, 256, 0, stream>>>(V, Wco, bco, cob, MROWS, ALLH, HID);
    gemm64_kernel<true, true><<<g, 256, 0, stream>>>(yb, pw, sep_bias, kcb, MROWS, ALLH, HID);

    // 3. span-dynamic-conv kernel weights + softmax
    spankern_kernel<<<MROWS / 4, 256, 0, stream>>>(kcb, qb, Wck, bck, kern);

    // 4. conv branch output (channels 384..767)
    convout_kernel<<<(MROWS * ALLH + 255) / 256, 256, 0, stream>>>(cob, kern, out);

    // 5. fused monotonic attention (channels 0..383)
    attn_kernel<<<BATCH * HEADS * (SEQ / ROWS), 256, 0, stream>>>(qb, kb, vb, mask, gammas, out);
}

// Round 2
// 1199.995 us; speedup vs baseline: 1.3104x; 1.3104x over previous
//
#include <hip/hip_runtime.h>
#include <math.h>

#define BATCH 8
#define SEQ   1024
#define HID   768
#define HEADS 6
#define DHEAD 64
#define ALLH  384   // HEADS*DHEAD
#define KS    9
#define PADC  4
#define MROWS (BATCH*SEQ)  // 8192

__device__ __forceinline__ float bcastf(float v, int l) {
    return __int_as_float(__builtin_amdgcn_readlane(__float_as_int(v), l));
}

// ---------------- depthwise conv on K (float4 over channels) ----------------
__global__ __launch_bounds__(256) void dconv_kernel(const float* __restrict__ Kin,
                                                    const float* __restrict__ dw,
                                                    float* __restrict__ y) {
    int idx = blockIdx.x * 256 + threadIdx.x;
    if (idx >= MROWS * (HID / 4)) return;
    int c4 = idx % (HID / 4);
    int s = (idx / (HID / 4)) % SEQ;
    int b = idx / ((HID / 4) * SEQ);
    int c = c4 * 4;
    float4 acc = {0.f, 0.f, 0.f, 0.f};
#pragma unroll
    for (int t = 0; t < KS; ++t) {
        int sj = s + t - PADC;
        if (sj >= 0 && sj < SEQ) {
            const float4 kv = *reinterpret_cast<const float4*>(&Kin[((size_t)b * SEQ + sj) * HID + c]);
            acc.x += kv.x * dw[(c + 0) * KS + t];
            acc.y += kv.y * dw[(c + 1) * KS + t];
            acc.z += kv.z * dw[(c + 2) * KS + t];
            acc.w += kv.w * dw[(c + 3) * KS + t];
        }
    }
    *reinterpret_cast<float4*>(&y[((size_t)b * SEQ + s) * HID + c]) = acc;
}

// ---------------- fp32 tiled GEMM: C[M,N] = A[M,K] @ B (+bias) ----------------
// BT=false: B stored [K,N]. BT=true: B stored [N,K].
template <bool BT, bool HAS_BIAS>
__global__ __launch_bounds__(256) void gemm64_kernel(const float* __restrict__ A,
                                                     const float* __restrict__ B,
                                                     const float* __restrict__ bias,
                                                     float* __restrict__ C,
                                                     int M, int N, int Kd) {
    __shared__ __align__(16) float As[16][68];
    __shared__ __align__(16) float Bs[16][68];
    int m0 = blockIdx.x * 64;
    int n0 = blockIdx.y * 64;
    int tid = threadIdx.x;
    int tx = tid & 15, ty = tid >> 4;
    int sm = tid >> 2;          // 0..63 tile row
    int sk = (tid & 3) * 4;     // k sub-offset
    float acc[4][4] = {};
    for (int k0 = 0; k0 < Kd; k0 += 16) {
        const float4 av = *reinterpret_cast<const float4*>(&A[(size_t)(m0 + sm) * Kd + k0 + sk]);
        As[sk + 0][sm] = av.x; As[sk + 1][sm] = av.y; As[sk + 2][sm] = av.z; As[sk + 3][sm] = av.w;
        if (BT) {
            const float4 bv = *reinterpret_cast<const float4*>(&B[(size_t)(n0 + sm) * Kd + k0 + sk]);
            Bs[sk + 0][sm] = bv.x; Bs[sk + 1][sm] = bv.y; Bs[sk + 2][sm] = bv.z; Bs[sk + 3][sm] = bv.w;
        } else {
            int bk = tid >> 4;          // 0..15
            int bn = (tid & 15) * 4;    // 0..60
            const float4 bv = *reinterpret_cast<const float4*>(&B[(size_t)(k0 + bk) * N + n0 + bn]);
            *reinterpret_cast<float4*>(&Bs[bk][bn]) = bv;
        }
        __syncthreads();
#pragma unroll
        for (int kk = 0; kk < 16; ++kk) {
            const float4 a4 = *reinterpret_cast<const float4*>(&As[kk][ty * 4]);
            const float4 b4 = *reinterpret_cast<const float4*>(&Bs[kk][tx * 4]);
            float a[4] = {a4.x, a4.y, a4.z, a4.w};
            float bb[4] = {b4.x, b4.y, b4.z, b4.w};
#pragma unroll
            for (int i = 0; i < 4; ++i)
#pragma unroll
                for (int j = 0; j < 4; ++j) acc[i][j] += a[i] * bb[j];
        }
        __syncthreads();
    }
#pragma unroll
    for (int i = 0; i < 4; ++i) {
        int m = m0 + ty * 4 + i;
#pragma unroll
        for (int j = 0; j < 4; ++j) {
            int n = n0 + tx * 4 + j;
            float v = acc[i][j];
            if (HAS_BIAS) v += bias[n];
            C[(size_t)m * N + n] = v;
        }
    }
}

// ---------------- span kernel: kern = softmax((keyconv*q) @ Wck + bck) over 9 taps ----------------
__global__ __launch_bounds__(256) void spankern_kernel(const float* __restrict__ keyconv,
                                                       const float* __restrict__ q,
                                                       const float* __restrict__ Wck,
                                                       const float* __restrict__ bck,
                                                       float* __restrict__ kern_sm) {
    __shared__ float ca[4][ALLH];
    __shared__ float kv[4][64];
    int row0 = blockIdx.x * 4;
    int tid = threadIdx.x;
    int r = tid >> 6;
    int lane = tid & 63;
    int row = row0 + r;
    for (int e = lane; e < ALLH; e += 64) {
        size_t off = (size_t)row * ALLH + e;
        ca[r][e] = keyconv[off] * q[off];
    }
    __syncthreads();
    float val = 0.f;
    if (lane < HEADS * KS) {
        for (int kidx = 0; kidx < ALLH; ++kidx)
            val += ca[r][kidx] * Wck[kidx * (HEADS * KS) + lane];
        val += bck[lane];
    }
    kv[r][lane] = val;
    __syncthreads();
    if (lane < HEADS) {
        float mx = -INFINITY;
#pragma unroll
        for (int t = 0; t < KS; ++t) mx = fmaxf(mx, kv[r][lane * KS + t]);
        float e[KS];
        float sum = 0.f;
#pragma unroll
        for (int t = 0; t < KS; ++t) {
            e[t] = expf(kv[r][lane * KS + t] - mx);
            sum += e[t];
        }
        float inv = 1.f / sum;
#pragma unroll
        for (int t = 0; t < KS; ++t)
            kern_sm[((size_t)row * HEADS + lane) * KS + t] = e[t] * inv;
    }
}

// ---------------- conv_out (float4 over channels) ----------------
__global__ __launch_bounds__(256) void convout_kernel(const float* __restrict__ co,
                                                      const float* __restrict__ kern_sm,
                                                      float* __restrict__ out) {
    int idx = blockIdx.x * 256 + threadIdx.x;
    if (idx >= MROWS * (ALLH / 4)) return;
    int c4 = idx % (ALLH / 4);
    int s = (idx / (ALLH / 4)) % SEQ;
    int b = idx / ((ALLH / 4) * SEQ);
    int c = c4 * 4;
    int h = c >> 6;
    const float* ks = &kern_sm[(((size_t)b * SEQ + s) * HEADS + h) * KS];
    float kt[KS];
#pragma unroll
    for (int t = 0; t < KS; ++t) kt[t] = ks[t];
    float4 acc = {0.f, 0.f, 0.f, 0.f};
#pragma unroll
    for (int t = 0; t < KS; ++t) {
        int sj = s + t - PADC;
        if (sj >= 0 && sj < SEQ) {
            const float4 cv = *reinterpret_cast<const float4*>(&co[((size_t)b * SEQ + sj) * ALLH + c]);
            acc.x += cv.x * kt[t];
            acc.y += cv.y * kt[t];
            acc.z += cv.z * kt[t];
            acc.w += cv.w * kt[t];
        }
    }
    *reinterpret_cast<float4*>(&out[((size_t)b * SEQ + s) * (2 * ALLH) + ALLH + c]) = acc;
}

// ---------------- fused monotonic attention ----------------
// 256 threads = 4 waves; wave w owns query rows (i0+w, i0+w+4); lane l owns columns {c*64+l}.
#define ROWS 8

template <int SLOT>
__device__ __forceinline__ float softmax_row(float (&sc)[16], int lane, int i, float gamma,
                                             unsigned mbits, float2* sp) {
    // masked row max
    float mx = -INFINITY;
#pragma unroll
    for (int c = 0; c < 16; ++c)
        if ((mbits >> c) & 1) mx = fmaxf(mx, sc[c]);
#pragma unroll
    for (int off = 32; off; off >>= 1) mx = fmaxf(mx, __shfl_xor(mx, off, 64));

    // exp + exact-order cumulative sum (j = c*64 + lane)
    float cum[16];
    float base = 0.f;
#pragma unroll
    for (int c = 0; c < 16; ++c) {
        float e = ((mbits >> c) & 1) ? expf(sc[c] - mx) : 0.f;
        float incl = e;
#pragma unroll
        for (int off = 1; off < 64; off <<= 1) {
            float nb = __shfl_up(incl, off, 64);
            if (lane >= off) incl += nb;
        }
        cum[c] = base + incl;
        base += __shfl(incl, 63, 64);
    }
    float tot = base;
    float inv_tot = tot > 0.f ? 1.f / tot : 0.f;

    // monotonic distance effect -> scores2 (overwrite sc), track m2
    float m2 = -INFINITY;
#pragma unroll
    for (int c = 0; c < 16; ++c) {
        float rem = (tot - cum[c]) * inv_tot;
        float pos = fabsf((float)(i - (c * 64 + lane)));
        float dist = sqrtf(fmaxf(rem * pos, 0.f));
        float eff = fminf(fmaxf(expf(dist * gamma), 1e-5f), 1e5f);
        float s2 = ((mbits >> c) & 1) ? sc[c] * eff : -1e8f;
        sc[c] = s2;
        m2 = fmaxf(m2, s2);
    }
#pragma unroll
    for (int off = 32; off; off >>= 1) m2 = fmaxf(m2, __shfl_xor(m2, off, 64));

    // second softmax numerators -> LDS (stride-1, conflict-free), sum
    float sum2 = 0.f;
#pragma unroll
    for (int c = 0; c < 16; ++c) {
        float e2 = expf(sc[c] - m2);
        sum2 += e2;
        reinterpret_cast<float*>(&sp[c * 64 + lane])[SLOT] = e2;
    }
#pragma unroll
    for (int off = 32; off; off >>= 1) sum2 += __shfl_xor(sum2, off, 64);
    return 1.f / sum2;
}

__global__ __launch_bounds__(256, 3) void attn_kernel(const float* __restrict__ q,
                                                      const float* __restrict__ k,
                                                      const float* __restrict__ v,
                                                      const int* __restrict__ mask,
                                                      const float* __restrict__ gammas,
                                                      float* __restrict__ out) {
    __shared__ float tile[64][65];     // 16.25 KB  (bank = (row+col)%32 -> conflict-free)
    __shared__ float2 s_p[4][SEQ];     // 32 KB     wave-private probs, rows (w, w+4) interleaved

    int blk = blockIdx.x;
    int i0 = (blk % (SEQ / ROWS)) * ROWS;
    int h = (blk / (SEQ / ROWS)) % HEADS;
    int b = blk / ((SEQ / ROWS) * HEADS);
    int tid = threadIdx.x;
    int lane = tid & 63;
    int w = tid >> 6;

    float g0 = gammas[h];
    float gamma = -(fmaxf(g0, 0.f) + log1pf(expf(-fabsf(g0))));  // -softplus

    const float* kb = k + ((size_t)b * SEQ) * ALLH + h * DHEAD;
    const float* vb = v + ((size_t)b * SEQ) * ALLH + h * DHEAD;
    const float* qb = q + ((size_t)(b * SEQ) + i0) * ALLH + h * DHEAD;

    // q rows in registers (lane l holds q[row][l]); fold in 1/sqrt(64)
    float qr0 = qb[(size_t)w * ALLH + lane] * 0.125f;
    float qr1 = qb[(size_t)(w + 4) * ALLH + lane] * 0.125f;

    // packed column mask (columns are lane-owned: j = c*64+lane)
    unsigned mbits = 0;
    const int* mrow = mask + b * SEQ;
#pragma unroll
    for (int c = 0; c < 16; ++c)
        if (mrow[c * 64 + lane] != 0) mbits |= (1u << c);

    // ---- scores: lane computes columns c*64+lane for rows w, w+4 ----
    float sc0[16], sc1[16];
#pragma unroll
    for (int c = 0; c < 16; ++c) {
        int j0 = c * 64;
        for (int e = tid; e < 1024; e += 256) {
            int jr = e >> 4, d4 = (e & 15) * 4;
            const float4 val = *reinterpret_cast<const float4*>(&kb[(size_t)(j0 + jr) * ALLH + d4]);
            tile[jr][d4 + 0] = val.x; tile[jr][d4 + 1] = val.y;
            tile[jr][d4 + 2] = val.z; tile[jr][d4 + 3] = val.w;
        }
        __syncthreads();
        float a0 = 0.f, a1 = 0.f;
#pragma unroll 16
        for (int d = 0; d < 64; ++d) {
            float kvv = tile[lane][d];
            a0 += bcastf(qr0, d) * kvv;   // v_readlane broadcast, no LDS op
            a1 += bcastf(qr1, d) * kvv;
        }
        sc0[c] = a0; sc1[c] = a1;
        __syncthreads();
    }

    // ---- softmax + monotonic modulation, fully in registers + shfl ----
    float inv0 = softmax_row<0>(sc0, lane, i0 + w, gamma, mbits, &s_p[w][0]);
    float inv1 = softmax_row<1>(sc1, lane, i0 + w + 4, gamma, mbits, &s_p[w][0]);

    // ---- PV ----
    float acc0 = 0.f, acc1 = 0.f;
    for (int j0 = 0; j0 < SEQ; j0 += 64) {
        for (int e = tid; e < 1024; e += 256) {
            int jr = e >> 4, d4 = (e & 15) * 4;
            const float4 val = *reinterpret_cast<const float4*>(&vb[(size_t)(j0 + jr) * ALLH + d4]);
            tile[jr][d4 + 0] = val.x; tile[jr][d4 + 1] = val.y;
            tile[jr][d4 + 2] = val.z; tile[jr][d4 + 3] = val.w;
        }
        __syncthreads();
        const float2* prow = &s_p[w][j0];
#pragma unroll 8
        for (int jr = 0; jr < 64; ++jr) {
            float vv = tile[jr][lane];
            float2 p = prow[jr];        // b64 broadcast, conflict-free
            acc0 += p.x * vv;
            acc1 += p.y * vv;
        }
        __syncthreads();
    }
    size_t ob = ((size_t)(b * SEQ) + i0) * (2 * ALLH) + h * DHEAD + lane;
    out[ob + (size_t)w * (2 * ALLH)] = acc0 * inv0;
    out[ob + (size_t)(w + 4) * (2 * ALLH)] = acc1 * inv1;
}

// ---------------- launch ----------------
extern "C" void kernel_launch(void* const* d_in, const int* in_sizes, int n_in,
                              void* d_out, int out_size, void* d_ws, size_t ws_size,
                              hipStream_t stream) {
    const float* Q = (const float*)d_in[0];
    const float* Kin = (const float*)d_in[1];
    const float* V = (const float*)d_in[2];
    const float* Wq = (const float*)d_in[3];
    const float* Wk = (const float*)d_in[4];
    const float* Wv = (const float*)d_in[5];
    const float* dw = (const float*)d_in[6];
    const float* pw = (const float*)d_in[7];
    const float* sep_bias = (const float*)d_in[8];
    const float* Wck = (const float*)d_in[9];
    const float* bck = (const float*)d_in[10];
    const float* Wco = (const float*)d_in[11];
    const float* bco = (const float*)d_in[12];
    const float* gammas = (const float*)d_in[13];
    const int* mask = (const int*)d_in[14];
    float* out = (float*)d_out;
    float* ws = (float*)d_ws;

    float* qb  = ws;                           // 8192*384
    float* kb  = qb + (size_t)MROWS * ALLH;
    float* vb  = kb + (size_t)MROWS * ALLH;
    float* cob = vb + (size_t)MROWS * ALLH;
    float* kcb = cob + (size_t)MROWS * ALLH;
    float* yb  = kcb + (size_t)MROWS * ALLH;   // 8192*768
    float* kern = yb + (size_t)MROWS * HID;    // 8192*54

    // 1. depthwise conv on K
    dconv_kernel<<<(MROWS * (HID / 4) + 255) / 256, 256, 0, stream>>>(Kin, dw, yb);

    // 2. projection GEMMs
    dim3 g(MROWS / 64, ALLH / 64);
    gemm64_kernel<false, false><<<g, 256, 0, stream>>>(Q, Wq, nullptr, qb, MROWS, ALLH, HID);
    gemm64_kernel<false, false><<<g, 256, 0, stream>>>(Kin, Wk, nullptr, kb, MROWS, ALLH, HID);
    gemm64_kernel<false, false><<<g, 256, 0, stream>>>(V, Wv, nullptr, vb, MROWS, ALLH, HID);
    gemm64_kernel<false, true><<<g, 256, 0, stream>>>(V, Wco, bco, cob, MROWS, ALLH, HID);
    gemm64_kernel<true, true><<<g, 256, 0, stream>>>(yb, pw, sep_bias, kcb, MROWS, ALLH, HID);

    // 3. span-dynamic-conv kernel weights + softmax
    spankern_kernel<<<MROWS / 4, 256, 0, stream>>>(kcb, qb, Wck, bck, kern);

    // 4. conv branch output (channels 384..767)
    convout_kernel<<<(MROWS * (ALLH / 4) + 255) / 256, 256, 0, stream>>>(cob, kern, out);

    // 5. fused monotonic attention (channels 0..383)
    attn_kernel<<<BATCH * HEADS * (SEQ / ROWS), 256, 0, stream>>>(qb, kb, vb, mask, gammas, out);
}

// Round 5
// 568.184 us; speedup vs baseline: 2.7676x; 2.1120x over previous
//
#include <hip/hip_runtime.h>
#include <math.h>

#define BATCH 8
#define SEQ   1024
#define HID   768
#define HEADS 6
#define DHEAD 64
#define ALLH  384   // HEADS*DHEAD
#define KS    9
#define PADC  4
#define MROWS (BATCH*SEQ)  // 8192

typedef __attribute__((ext_vector_type(8))) short bf16x8;
typedef __attribute__((ext_vector_type(4))) short bf16x4;
typedef __attribute__((ext_vector_type(4))) float f32x4;

__device__ __forceinline__ ushort f2bf(float x) {   // RTN-even f32 -> bf16 bits
    unsigned u = __float_as_uint(x);
    unsigned r = (u + 0x7FFFu + ((u >> 16) & 1u)) >> 16;
    return (ushort)r;
}

__device__ __forceinline__ void mfma16(f32x4& c4, bf16x4 a, bf16x4 b) {
#if __has_builtin(__builtin_amdgcn_mfma_f32_16x16x16bf16_1k)
    c4 = __builtin_amdgcn_mfma_f32_16x16x16bf16_1k(a, b, c4, 0, 0, 0);
#else
    asm volatile("v_mfma_f32_16x16x16_bf16 %0, %1, %2, %0" : "+v"(c4) : "v"(a), "v"(b));
#endif
}

// ---------------- depthwise conv on K (float4 over channels) ----------------
__global__ __launch_bounds__(256) void dconv_kernel(const float* __restrict__ Kin,
                                                    const float* __restrict__ dw,
                                                    float* __restrict__ y) {
    int idx = blockIdx.x * 256 + threadIdx.x;
    if (idx >= MROWS * (HID / 4)) return;
    int c4 = idx % (HID / 4);
    int s = (idx / (HID / 4)) % SEQ;
    int b = idx / ((HID / 4) * SEQ);
    int c = c4 * 4;
    float4 acc = {0.f, 0.f, 0.f, 0.f};
#pragma unroll
    for (int t = 0; t < KS; ++t) {
        int sj = s + t - PADC;
        if (sj >= 0 && sj < SEQ) {
            const float4 kv = *reinterpret_cast<const float4*>(&Kin[((size_t)b * SEQ + sj) * HID + c]);
            acc.x += kv.x * dw[(c + 0) * KS + t];
            acc.y += kv.y * dw[(c + 1) * KS + t];
            acc.z += kv.z * dw[(c + 2) * KS + t];
            acc.w += kv.w * dw[(c + 3) * KS + t];
        }
    }
    *reinterpret_cast<float4*>(&y[((size_t)b * SEQ + s) * HID + c]) = acc;
}

// ---------------- fp32 tiled GEMM: C[M,N] = A[M,K] @ B (+bias) ----------------
// BT=false: B stored [K,N]. BT=true: B stored [N,K].
// BMODE: 0 = f32 only, 1 = f32 + bf16 head-major, 2 = bf16 head-major only
template <bool BT, bool HAS_BIAS, int BMODE>
__global__ __launch_bounds__(256) void gemm64_kernel(const float* __restrict__ A,
                                                     const float* __restrict__ B,
                                                     const float* __restrict__ bias,
                                                     float* __restrict__ C,
                                                     ushort* __restrict__ Chm,
                                                     int M, int N, int Kd) {
    __shared__ __align__(16) float As[16][68];
    __shared__ __align__(16) float Bs[16][68];
    int m0 = blockIdx.x * 64;
    int n0 = blockIdx.y * 64;
    int tid = threadIdx.x;
    int tx = tid & 15, ty = tid >> 4;
    int sm = tid >> 2;
    int sk = (tid & 3) * 4;
    float acc[4][4] = {};
    for (int k0 = 0; k0 < Kd; k0 += 16) {
        const float4 av = *reinterpret_cast<const float4*>(&A[(size_t)(m0 + sm) * Kd + k0 + sk]);
        As[sk + 0][sm] = av.x; As[sk + 1][sm] = av.y; As[sk + 2][sm] = av.z; As[sk + 3][sm] = av.w;
        if (BT) {
            const float4 bv = *reinterpret_cast<const float4*>(&B[(size_t)(n0 + sm) * Kd + k0 + sk]);
            Bs[sk + 0][sm] = bv.x; Bs[sk + 1][sm] = bv.y; Bs[sk + 2][sm] = bv.z; Bs[sk + 3][sm] = bv.w;
        } else {
            int bk = tid >> 4;
            int bn = (tid & 15) * 4;
            const float4 bv = *reinterpret_cast<const float4*>(&B[(size_t)(k0 + bk) * N + n0 + bn]);
            *reinterpret_cast<float4*>(&Bs[bk][bn]) = bv;
        }
        __syncthreads();
#pragma unroll
        for (int kk = 0; kk < 16; ++kk) {
            const float4 a4 = *reinterpret_cast<const float4*>(&As[kk][ty * 4]);
            const float4 b4 = *reinterpret_cast<const float4*>(&Bs[kk][tx * 4]);
            float a[4] = {a4.x, a4.y, a4.z, a4.w};
            float bb[4] = {b4.x, b4.y, b4.z, b4.w};
#pragma unroll
            for (int i = 0; i < 4; ++i)
#pragma unroll
                for (int j = 0; j < 4; ++j) acc[i][j] += a[i] * bb[j];
        }
        __syncthreads();
    }
#pragma unroll
    for (int i = 0; i < 4; ++i) {
        int m = m0 + ty * 4 + i;
        if (BMODE != 2) {
#pragma unroll
            for (int j = 0; j < 4; ++j) {
                int n = n0 + tx * 4 + j;
                float v = acc[i][j];
                if (HAS_BIAS) v += bias[n];
                C[(size_t)m * N + n] = v;
            }
        }
        if (BMODE != 0) {
            int bb = m >> 10, s = m & 1023;     // SEQ = 1024
            int n = n0 + tx * 4;
            int head = n >> 6, d = n & 63;
            size_t off = (((size_t)bb * HEADS + head) * SEQ + s) * 64 + d;
            ushort4 u;
            u.x = f2bf(acc[i][0]); u.y = f2bf(acc[i][1]);
            u.z = f2bf(acc[i][2]); u.w = f2bf(acc[i][3]);
            *reinterpret_cast<ushort4*>(&Chm[off]) = u;
        }
    }
}

// ---------------- span kernel: kern = softmax((keyconv*q) @ Wck + bck) over 9 taps ----------------
__global__ __launch_bounds__(256) void spankern_kernel(const float* __restrict__ keyconv,
                                                       const float* __restrict__ q,
                                                       const float* __restrict__ Wck,
                                                       const float* __restrict__ bck,
                                                       float* __restrict__ kern_sm) {
    __shared__ float ca[4][ALLH];
    __shared__ float kv[4][64];
    int row0 = blockIdx.x * 4;
    int tid = threadIdx.x;
    int r = tid >> 6;
    int lane = tid & 63;
    int row = row0 + r;
    for (int e = lane; e < ALLH; e += 64) {
        size_t off = (size_t)row * ALLH + e;
        ca[r][e] = keyconv[off] * q[off];
    }
    __syncthreads();
    float val = 0.f;
    if (lane < HEADS * KS) {
        for (int kidx = 0; kidx < ALLH; ++kidx)
            val += ca[r][kidx] * Wck[kidx * (HEADS * KS) + lane];
        val += bck[lane];
    }
    kv[r][lane] = val;
    __syncthreads();
    if (lane < HEADS) {
        float mx = -INFINITY;
#pragma unroll
        for (int t = 0; t < KS; ++t) mx = fmaxf(mx, kv[r][lane * KS + t]);
        float e[KS];
        float sum = 0.f;
#pragma unroll
        for (int t = 0; t < KS; ++t) {
            e[t] = expf(kv[r][lane * KS + t] - mx);
            sum += e[t];
        }
        float inv = 1.f / sum;
#pragma unroll
        for (int t = 0; t < KS; ++t)
            kern_sm[((size_t)row * HEADS + lane) * KS + t] = e[t] * inv;
    }
}

// ---------------- conv_out (float4 over channels) ----------------
__global__ __launch_bounds__(256) void convout_kernel(const float* __restrict__ co,
                                                      const float* __restrict__ kern_sm,
                                                      float* __restrict__ out) {
    int idx = blockIdx.x * 256 + threadIdx.x;
    if (idx >= MROWS * (ALLH / 4)) return;
    int c4 = idx % (ALLH / 4);
    int s = (idx / (ALLH / 4)) % SEQ;
    int b = idx / ((ALLH / 4) * SEQ);
    int c = c4 * 4;
    int h = c >> 6;
    const float* ks = &kern_sm[(((size_t)b * SEQ + s) * HEADS + h) * KS];
    float kt[KS];
#pragma unroll
    for (int t = 0; t < KS; ++t) kt[t] = ks[t];
    float4 acc = {0.f, 0.f, 0.f, 0.f};
#pragma unroll
    for (int t = 0; t < KS; ++t) {
        int sj = s + t - PADC;
        if (sj >= 0 && sj < SEQ) {
            const float4 cv = *reinterpret_cast<const float4*>(&co[((size_t)b * SEQ + sj) * ALLH + c]);
            acc.x += cv.x * kt[t];
            acc.y += cv.y * kt[t];
            acc.z += cv.z * kt[t];
            acc.w += cv.w * kt[t];
        }
    }
    *reinterpret_cast<float4*>(&out[((size_t)b * SEQ + s) * (2 * ALLH) + ALLH + c]) = acc;
}

// ---------------- fused monotonic attention, MFMA version ----------------
// 4 waves/block, wave w owns q rows i0 + w*16 .. +15 of one (b,h). QBLK=64.
// Swapped QK^T: mfma(K_frag, Q_frag) -> C[key][q]; softmax stats per q=lane&15.
// PV: P tile (C-layout) IS the A-frag of mfma_16x16x16; V kept TRANSPOSED in
// LDS (vbufT[d][key], stride 68) so the B-frag's 4 key-elements are one
// contiguous ds_read_b64 -- no tr_b16, no layout ambiguity.
__global__ __launch_bounds__(256) void attn_mfma(const ushort* __restrict__ qh,
                                                 const ushort* __restrict__ kh,
                                                 const ushort* __restrict__ vh,
                                                 const int* __restrict__ mask,
                                                 const float* __restrict__ gammas,
                                                 float* __restrict__ out) {
    __shared__ __align__(16) ushort kbuf[64 * 64];    // row-major [key][d], XOR-swizzled 16B chunks
    __shared__ __align__(16) ushort vbufT[64 * 68];   // transposed [d][key], pad stride 68
    __shared__ float s_msk[SEQ];

    const int blk = blockIdx.x;
    const int qt = blk & 15;                  // SEQ/QBLK = 16
    const int h = (blk >> 4) % HEADS;
    const int b = blk / (16 * HEADS);
    const int i0 = qt * 64;
    const int tid = threadIdx.x;
    const int lane = tid & 63;
    const int w = tid >> 6;
    const int g = lane >> 4;   // 0..3
    const int c = lane & 15;

    float g0 = gammas[h];
    float gamma = -(fmaxf(g0, 0.f) + log1pf(expf(-fabsf(g0))));  // -softplus

    const ushort* khb = kh + ((size_t)b * HEADS + h) * SEQ * 64;
    const ushort* vhb = vh + ((size_t)b * HEADS + h) * SEQ * 64;
    const ushort* qhb = qh + ((size_t)b * HEADS + h) * SEQ * 64;

    for (int e = tid; e < SEQ; e += 256)
        s_msk[e] = (mask[b * SEQ + e] != 0) ? 1.f : 0.f;

    // Q B-fragments: row q = i0 + w*16 + c, k(d) = ks*32 + g*8 + e
    bf16x8 qf0, qf1;
    {
        const ushort* qrow = qhb + (size_t)(i0 + w * 16 + c) * 64 + g * 8;
        qf0 = *reinterpret_cast<const bf16x8*>(qrow);
        qf1 = *reinterpret_cast<const bf16x8*>(qrow + 32);
    }

    // ================= pass 1: raw denominator T per q-row =================
    float Tacc = 0.f;
    for (int chk = 0; chk < 16; ++chk) {
        const int j0 = chk * 64;
        __syncthreads();
#pragma unroll
        for (int it = 0; it < 2; ++it) {
            int gg = tid + it * 256;
            int row = gg >> 3, cc = gg & 7;
            uint4 val = *reinterpret_cast<const uint4*>(khb + (size_t)(j0 + row) * 64 + cc * 8);
            int boff = row * 128 + ((cc * 16) ^ ((row & 7) << 4));
            *reinterpret_cast<uint4*>((char*)kbuf + boff) = val;
        }
        __syncthreads();
#pragma unroll
        for (int m = 0; m < 4; ++m) {
            f32x4 acc = {0.f, 0.f, 0.f, 0.f};
            int row = m * 16 + c;
            int sw = (row & 7) << 4;
            bf16x8 kf0 = *reinterpret_cast<const bf16x8*>((char*)kbuf + row * 128 + ((g * 16) ^ sw));
            bf16x8 kf1 = *reinterpret_cast<const bf16x8*>((char*)kbuf + row * 128 + ((64 + g * 16) ^ sw));
            acc = __builtin_amdgcn_mfma_f32_16x16x32_bf16(kf0, qf0, acc, 0, 0, 0);
            acc = __builtin_amdgcn_mfma_f32_16x16x32_bf16(kf1, qf1, acc, 0, 0, 0);
#pragma unroll
            for (int r = 0; r < 4; ++r) {
                float mk = s_msk[j0 + m * 16 + g * 4 + r];
                Tacc += mk * __expf(acc[r] * 0.125f);
            }
        }
    }
    Tacc += __shfl_xor(Tacc, 16, 64);
    Tacc += __shfl_xor(Tacc, 32, 64);
    const float T = Tacc;
    const float invT = (T > 0.f) ? 1.f / T : 0.f;

    // ================= pass 2: cum, effect, second softmax, PV =================
    f32x4 ctx0 = {0,0,0,0}, ctx1 = {0,0,0,0}, ctx2 = {0,0,0,0}, ctx3 = {0,0,0,0};
    float l2acc = 0.f;
    float base = 0.f;
    const float iq = (float)(i0 + w * 16 + c);

    for (int chk = 0; chk < 16; ++chk) {
        const int j0 = chk * 64;
        __syncthreads();
#pragma unroll
        for (int it = 0; it < 2; ++it) {
            int gg = tid + it * 256;
            int row = gg >> 3, cc = gg & 7;       // row = key-in-tile, cc*8 = d base
            const size_t goff = (size_t)(j0 + row) * 64 + cc * 8;
            uint4 kval = *reinterpret_cast<const uint4*>(khb + goff);
            int boff = row * 128 + ((cc * 16) ^ ((row & 7) << 4));
            *reinterpret_cast<uint4*>((char*)kbuf + boff) = kval;
            uint4 vval = *reinterpret_cast<const uint4*>(vhb + goff);
            ushort hw8[8];
            hw8[0] = (ushort)(vval.x & 0xffff); hw8[1] = (ushort)(vval.x >> 16);
            hw8[2] = (ushort)(vval.y & 0xffff); hw8[3] = (ushort)(vval.y >> 16);
            hw8[4] = (ushort)(vval.z & 0xffff); hw8[5] = (ushort)(vval.z >> 16);
            hw8[6] = (ushort)(vval.w & 0xffff); hw8[7] = (ushort)(vval.w >> 16);
#pragma unroll
            for (int q = 0; q < 8; ++q) {
                int dd = q ^ (row & 7);           // rotate store order: spread banks
                vbufT[(cc * 8 + dd) * 68 + row] = hw8[dd];
            }
        }
        __syncthreads();
#pragma unroll
        for (int m = 0; m < 4; ++m) {
            f32x4 acc = {0.f, 0.f, 0.f, 0.f};
            int row = m * 16 + c;
            int sw = (row & 7) << 4;
            bf16x8 kf0 = *reinterpret_cast<const bf16x8*>((char*)kbuf + row * 128 + ((g * 16) ^ sw));
            bf16x8 kf1 = *reinterpret_cast<const bf16x8*>((char*)kbuf + row * 128 + ((64 + g * 16) ^ sw));
            acc = __builtin_amdgcn_mfma_f32_16x16x32_bf16(kf0, qf0, acc, 0, 0, 0);
            acc = __builtin_amdgcn_mfma_f32_16x16x32_bf16(kf1, qf1, acc, 0, 0, 0);

            float e[4], s[4], mk[4], incl[4];
            float li = 0.f;
#pragma unroll
            for (int r = 0; r < 4; ++r) {
                mk[r] = s_msk[j0 + m * 16 + g * 4 + r];
                s[r] = acc[r] * 0.125f;
                e[r] = mk[r] * __expf(s[r]);
                li += e[r];
                incl[r] = li;
            }
            // inclusive scan over the 4 key-groups g (keys m*16 + g*4 + r)
            float gs = li;
            float up = __shfl_up(gs, 16, 64); if (g >= 1) gs += up;
            up = __shfl_up(gs, 32, 64); if (g >= 2) gs += up;
            float gexcl = gs - li;
            float ttot = __shfl(gs, 48 + c, 64);   // tile total from g=3, same q

            float p2[4];
#pragma unroll
            for (int r = 0; r < 4; ++r) {
                float cum = base + gexcl + incl[r];
                float rem = fmaxf((T - cum) * invT, 0.f);
                float jf = (float)(j0 + m * 16 + g * 4 + r);
                float pos = fabsf(iq - jf);
                float dist = sqrtf(rem * pos);
                float eff = fminf(fmaxf(__expf(dist * gamma), 1e-5f), 1e5f);
                float s2 = (mk[r] != 0.f) ? s[r] * eff : -1e8f;
                p2[r] = __expf(s2);
                l2acc += p2[r];
            }
            base += ttot;

            bf16x4 pa;
            pa[0] = (short)f2bf(p2[0]); pa[1] = (short)f2bf(p2[1]);
            pa[2] = (short)f2bf(p2[2]); pa[3] = (short)f2bf(p2[3]);

            // B-frag: lane (g,c) needs V[16m + g*4 + e][16t + c] -> contiguous in vbufT
            const int vo = 16 * m + 4 * g;
            bf16x4 v0 = *reinterpret_cast<const bf16x4*>(&vbufT[(c +  0) * 68 + vo]);
            bf16x4 v1 = *reinterpret_cast<const bf16x4*>(&vbufT[(c + 16) * 68 + vo]);
            bf16x4 v2 = *reinterpret_cast<const bf16x4*>(&vbufT[(c + 32) * 68 + vo]);
            bf16x4 v3 = *reinterpret_cast<const bf16x4*>(&vbufT[(c + 48) * 68 + vo]);
            mfma16(ctx0, pa, v0);
            mfma16(ctx1, pa, v1);
            mfma16(ctx2, pa, v2);
            mfma16(ctx3, pa, v3);
        }
    }
    l2acc += __shfl_xor(l2acc, 16, 64);
    l2acc += __shfl_xor(l2acc, 32, 64);
    const float invl2 = 1.f / l2acc;

#pragma unroll
    for (int r = 0; r < 4; ++r) {
        float inv_r = __shfl(invl2, g * 4 + r, 64);   // stats live at lanes with (lane&15)==q
        int qrow = i0 + w * 16 + g * 4 + r;
        float* orow = out + ((size_t)b * SEQ + qrow) * (2 * ALLH) + h * DHEAD;
        orow[c +  0] = ctx0[r] * inv_r;
        orow[c + 16] = ctx1[r] * inv_r;
        orow[c + 32] = ctx2[r] * inv_r;
        orow[c + 48] = ctx3[r] * inv_r;
    }
}

// ---------------- launch ----------------
extern "C" void kernel_launch(void* const* d_in, const int* in_sizes, int n_in,
                              void* d_out, int out_size, void* d_ws, size_t ws_size,
                              hipStream_t stream) {
    const float* Q = (const float*)d_in[0];
    const float* Kin = (const float*)d_in[1];
    const float* V = (const float*)d_in[2];
    const float* Wq = (const float*)d_in[3];
    const float* Wk = (const float*)d_in[4];
    const float* Wv = (const float*)d_in[5];
    const float* dw = (const float*)d_in[6];
    const float* pw = (const float*)d_in[7];
    const float* sep_bias = (const float*)d_in[8];
    const float* Wck = (const float*)d_in[9];
    const float* bck = (const float*)d_in[10];
    const float* Wco = (const float*)d_in[11];
    const float* bco = (const float*)d_in[12];
    const float* gammas = (const float*)d_in[13];
    const int* mask = (const int*)d_in[14];
    float* out = (float*)d_out;
    float* ws = (float*)d_ws;

    const size_t NP = (size_t)MROWS * ALLH;        // 3145728
    float* qb   = ws;                              // f32 q (spankern)
    float* cob  = qb + NP;
    float* kcb  = cob + NP;
    float* yb   = kcb + NP;                        // MROWS*HID
    float* kern = yb + (size_t)MROWS * HID;        // MROWS*54
    ushort* qh  = (ushort*)(kern + (size_t)MROWS * HEADS * KS);
    ushort* khm = qh + NP;
    ushort* vhm = khm + NP;

    // 1. depthwise conv on K
    dconv_kernel<<<(MROWS * (HID / 4) + 255) / 256, 256, 0, stream>>>(Kin, dw, yb);

    // 2. projection GEMMs (fp32 math; bf16 head-major copies for attention)
    dim3 g(MROWS / 64, ALLH / 64);
    gemm64_kernel<false, false, 1><<<g, 256, 0, stream>>>(Q, Wq, nullptr, qb, qh, MROWS, ALLH, HID);
    gemm64_kernel<false, false, 2><<<g, 256, 0, stream>>>(Kin, Wk, nullptr, nullptr, khm, MROWS, ALLH, HID);
    gemm64_kernel<false, false, 2><<<g, 256, 0, stream>>>(V, Wv, nullptr, nullptr, vhm, MROWS, ALLH, HID);
    gemm64_kernel<false, true, 0><<<g, 256, 0, stream>>>(V, Wco, bco, cob, nullptr, MROWS, ALLH, HID);
    gemm64_kernel<true, true, 0><<<g, 256, 0, stream>>>(yb, pw, sep_bias, kcb, nullptr, MROWS, ALLH, HID);

    // 3. span-dynamic-conv kernel weights + softmax
    spankern_kernel<<<MROWS / 4, 256, 0, stream>>>(kcb, qb, Wck, bck, kern);

    // 4. conv branch output (channels 384..767)
    convout_kernel<<<(MROWS * (ALLH / 4) + 255) / 256, 256, 0, stream>>>(cob, kern, out);

    // 5. fused monotonic attention via MFMA (channels 0..383)
    attn_mfma<<<BATCH * HEADS * (SEQ / 64), 256, 0, stream>>>(qh, khm, vhm, mask, gammas, out);
}

// Round 6
// 339.397 us; speedup vs baseline: 4.6333x; 1.6741x over previous
//
#include <hip/hip_runtime.h>
#include <math.h>

#define BATCH 8
#define SEQ   1024
#define HID   768
#define HEADS 6
#define DHEAD 64
#define ALLH  384   // HEADS*DHEAD
#define KS    9
#define PADC  4
#define MROWS (BATCH*SEQ)  // 8192

typedef __attribute__((ext_vector_type(8))) short bf16x8;
typedef __attribute__((ext_vector_type(4))) short bf16x4;
typedef __attribute__((ext_vector_type(4))) float f32x4;

__device__ __forceinline__ ushort f2bf(float x) {   // RTN-even f32 -> bf16 bits
    unsigned u = __float_as_uint(x);
    unsigned r = (u + 0x7FFFu + ((u >> 16) & 1u)) >> 16;
    return (ushort)r;
}
__device__ __forceinline__ unsigned pk2(float a, float b) {
    return (unsigned)f2bf(a) | ((unsigned)f2bf(b) << 16);
}

__device__ __forceinline__ void mfma16(f32x4& c4, bf16x4 a, bf16x4 b) {
#if __has_builtin(__builtin_amdgcn_mfma_f32_16x16x16bf16_1k)
    c4 = __builtin_amdgcn_mfma_f32_16x16x16bf16_1k(a, b, c4, 0, 0, 0);
#else
    asm volatile("v_mfma_f32_16x16x16_bf16 %0, %1, %2, %0" : "+v"(c4) : "v"(a), "v"(b));
#endif
}

// ---------------- depthwise conv on K (float4 over channels) ----------------
__global__ __launch_bounds__(256) void dconv_kernel(const float* __restrict__ Kin,
                                                    const float* __restrict__ dw,
                                                    float* __restrict__ y) {
    int idx = blockIdx.x * 256 + threadIdx.x;
    if (idx >= MROWS * (HID / 4)) return;
    int c4 = idx % (HID / 4);
    int s = (idx / (HID / 4)) % SEQ;
    int b = idx / ((HID / 4) * SEQ);
    int c = c4 * 4;
    float4 acc = {0.f, 0.f, 0.f, 0.f};
#pragma unroll
    for (int t = 0; t < KS; ++t) {
        int sj = s + t - PADC;
        if (sj >= 0 && sj < SEQ) {
            const float4 kv = *reinterpret_cast<const float4*>(&Kin[((size_t)b * SEQ + sj) * HID + c]);
            acc.x += kv.x * dw[(c + 0) * KS + t];
            acc.y += kv.y * dw[(c + 1) * KS + t];
            acc.z += kv.z * dw[(c + 2) * KS + t];
            acc.w += kv.w * dw[(c + 3) * KS + t];
        }
    }
    *reinterpret_cast<float4*>(&y[((size_t)b * SEQ + s) * HID + c]) = acc;
}

// ---------------- weight transpose-convert: W[768,384] f32 -> Wt[384,768] bf16 ----------------
__global__ __launch_bounds__(256) void wcvt_kernel(const float* __restrict__ W0, const float* __restrict__ W1,
                                                   const float* __restrict__ W2, const float* __restrict__ W3,
                                                   ushort* __restrict__ O0, ushort* __restrict__ O1,
                                                   ushort* __restrict__ O2, ushort* __restrict__ O3) {
    __shared__ float t[32][33];
    int wsel = blockIdx.z;
    const float* W = wsel == 0 ? W0 : wsel == 1 ? W1 : wsel == 2 ? W2 : W3;
    ushort* O = wsel == 0 ? O0 : wsel == 1 ? O1 : wsel == 2 ? O2 : O3;
    int kt = blockIdx.x * 32;   // 768/32 = 24
    int nt = blockIdx.y * 32;   // 384/32 = 12
    int tx = threadIdx.x & 31, ty = threadIdx.x >> 5;  // ty 0..7
#pragma unroll
    for (int i = 0; i < 4; ++i)
        t[ty + i * 8][tx] = W[(size_t)(kt + ty + i * 8) * ALLH + nt + tx];
    __syncthreads();
#pragma unroll
    for (int i = 0; i < 4; ++i)
        O[(size_t)(nt + ty + i * 8) * HID + kt + tx] = f2bf(t[tx][ty + i * 8]);
}

// ---------------- pw convert (already [N=384, K=768]) ----------------
__global__ __launch_bounds__(256) void pwcvt_kernel(const float* __restrict__ pw, ushort* __restrict__ pwb) {
    int i = blockIdx.x * 256 + threadIdx.x;
    if (i < ALLH * HID) pwb[i] = f2bf(pw[i]);
}

// ---------------- bf16 MFMA GEMM: C[8192,384] = A[8192,768](f32, cvt on load) @ Bt[384,768]^T ----------------
// 64x64 tile, BK=64, 4 waves x (16 rows x 64 cols). BMODE: 0 f32 only, 1 both, 2 bf16 head-major only.
template <int BMODE, bool HAS_BIAS>
__global__ __launch_bounds__(256) void gemm_mfma(const float* __restrict__ A,
                                                 const ushort* __restrict__ Bt,
                                                 const float* __restrict__ bias,
                                                 float* __restrict__ C,
                                                 ushort* __restrict__ Chm) {
    __shared__ __align__(16) ushort As[64 * 64];   // [row][k] bf16, XOR-swizzled 16B chunks
    __shared__ __align__(16) ushort Bs[64 * 64];   // [col][k] bf16, same swizzle

    // bijective XCD swizzle (nwg = 768 = 8*96): consecutive n-tiles of one m-band share an XCD
    const int bid = blockIdx.x;
    const int swz = (bid & 7) * 96 + (bid >> 3);
    const int n0 = (swz % 6) * 64;
    const int m0 = (swz / 6) * 64;

    const int tid = threadIdx.x;
    const int lane = tid & 63;
    const int w = tid >> 6;
    const int g = lane >> 4;
    const int c = lane & 15;

    f32x4 acc[4] = {{0,0,0,0},{0,0,0,0},{0,0,0,0},{0,0,0,0}};

    for (int k0 = 0; k0 < HID; k0 += 64) {
        __syncthreads();
#pragma unroll
        for (int it = 0; it < 2; ++it) {
            int e = tid + it * 256;            // 0..511
            int row = e >> 3;                  // 0..63
            int c8 = (e & 7) * 8;              // k sub-offset (elems)
            int boff = row * 128 + ((c8 * 2) ^ ((row & 7) << 4));
            // A: f32 -> bf16
            const float4 f0 = *reinterpret_cast<const float4*>(&A[(size_t)(m0 + row) * HID + k0 + c8]);
            const float4 f1 = *reinterpret_cast<const float4*>(&A[(size_t)(m0 + row) * HID + k0 + c8 + 4]);
            uint4 p;
            p.x = pk2(f0.x, f0.y); p.y = pk2(f0.z, f0.w);
            p.z = pk2(f1.x, f1.y); p.w = pk2(f1.z, f1.w);
            *reinterpret_cast<uint4*>((char*)As + boff) = p;
            // B: bf16 direct
            const uint4 bv = *reinterpret_cast<const uint4*>(&Bt[(size_t)(n0 + row) * HID + k0 + c8]);
            *reinterpret_cast<uint4*>((char*)Bs + boff) = bv;
        }
        __syncthreads();

        const int arow = w * 16 + c;
        const int asw = (arow & 7) << 4;
        bf16x8 af0 = *reinterpret_cast<const bf16x8*>((char*)As + arow * 128 + ((g * 16) ^ asw));
        bf16x8 af1 = *reinterpret_cast<const bf16x8*>((char*)As + arow * 128 + ((64 + g * 16) ^ asw));
#pragma unroll
        for (int nq = 0; nq < 4; ++nq) {
            const int brow = nq * 16 + c;
            const int bsw = (brow & 7) << 4;
            bf16x8 bf0 = *reinterpret_cast<const bf16x8*>((char*)Bs + brow * 128 + ((g * 16) ^ bsw));
            bf16x8 bf1 = *reinterpret_cast<const bf16x8*>((char*)Bs + brow * 128 + ((64 + g * 16) ^ bsw));
            acc[nq] = __builtin_amdgcn_mfma_f32_16x16x32_bf16(af0, bf0, acc[nq], 0, 0, 0);
            acc[nq] = __builtin_amdgcn_mfma_f32_16x16x32_bf16(af1, bf1, acc[nq], 0, 0, 0);
        }
    }

#pragma unroll
    for (int nq = 0; nq < 4; ++nq) {
        const int n = n0 + nq * 16 + c;
        const float bv = HAS_BIAS ? bias[n] : 0.f;
#pragma unroll
        for (int r = 0; r < 4; ++r) {
            const int m = m0 + w * 16 + g * 4 + r;
            float v = acc[nq][r] + bv;
            if (BMODE != 2) C[(size_t)m * ALLH + n] = v;
            if (BMODE != 0) {
                int bb = m >> 10, s = m & 1023;
                int head = n >> 6, d = n & 63;
                Chm[(((size_t)bb * HEADS + head) * SEQ + s) * 64 + d] = f2bf(v);
            }
        }
    }
}

// ---------------- span kernel: kern = softmax((keyconv*q) @ Wck + bck) over 9 taps ----------------
__global__ __launch_bounds__(256) void spankern_kernel(const float* __restrict__ keyconv,
                                                       const float* __restrict__ q,
                                                       const float* __restrict__ Wck,
                                                       const float* __restrict__ bck,
                                                       float* __restrict__ kern_sm) {
    __shared__ float ca[4][ALLH];
    __shared__ float kv[4][64];
    int row0 = blockIdx.x * 4;
    int tid = threadIdx.x;
    int r = tid >> 6;
    int lane = tid & 63;
    int row = row0 + r;
    for (int e = lane; e < ALLH; e += 64) {
        size_t off = (size_t)row * ALLH + e;
        ca[r][e] = keyconv[off] * q[off];
    }
    __syncthreads();
    float val = 0.f;
    if (lane < HEADS * KS) {
        for (int kidx = 0; kidx < ALLH; ++kidx)
            val += ca[r][kidx] * Wck[kidx * (HEADS * KS) + lane];
        val += bck[lane];
    }
    kv[r][lane] = val;
    __syncthreads();
    if (lane < HEADS) {
        float mx = -INFINITY;
#pragma unroll
        for (int t = 0; t < KS; ++t) mx = fmaxf(mx, kv[r][lane * KS + t]);
        float e[KS];
        float sum = 0.f;
#pragma unroll
        for (int t = 0; t < KS; ++t) {
            e[t] = expf(kv[r][lane * KS + t] - mx);
            sum += e[t];
        }
        float inv = 1.f / sum;
#pragma unroll
        for (int t = 0; t < KS; ++t)
            kern_sm[((size_t)row * HEADS + lane) * KS + t] = e[t] * inv;
    }
}

// ---------------- conv_out (float4 over channels) ----------------
__global__ __launch_bounds__(256) void convout_kernel(const float* __restrict__ co,
                                                      const float* __restrict__ kern_sm,
                                                      float* __restrict__ out) {
    int idx = blockIdx.x * 256 + threadIdx.x;
    if (idx >= MROWS * (ALLH / 4)) return;
    int c4 = idx % (ALLH / 4);
    int s = (idx / (ALLH / 4)) % SEQ;
    int b = idx / ((ALLH / 4) * SEQ);
    int c = c4 * 4;
    int h = c >> 6;
    const float* ks = &kern_sm[(((size_t)b * SEQ + s) * HEADS + h) * KS];
    float kt[KS];
#pragma unroll
    for (int t = 0; t < KS; ++t) kt[t] = ks[t];
    float4 acc = {0.f, 0.f, 0.f, 0.f};
#pragma unroll
    for (int t = 0; t < KS; ++t) {
        int sj = s + t - PADC;
        if (sj >= 0 && sj < SEQ) {
            const float4 cv = *reinterpret_cast<const float4*>(&co[((size_t)b * SEQ + sj) * ALLH + c]);
            acc.x += cv.x * kt[t];
            acc.y += cv.y * kt[t];
            acc.z += cv.z * kt[t];
            acc.w += cv.w * kt[t];
        }
    }
    *reinterpret_cast<float4*>(&out[((size_t)b * SEQ + s) * (2 * ALLH) + ALLH + c]) = acc;
}

// ---------------- fused monotonic attention, MFMA version ----------------
__global__ __launch_bounds__(256) void attn_mfma(const ushort* __restrict__ qh,
                                                 const ushort* __restrict__ kh,
                                                 const ushort* __restrict__ vh,
                                                 const int* __restrict__ mask,
                                                 const float* __restrict__ gammas,
                                                 float* __restrict__ out) {
    __shared__ __align__(16) ushort kbuf[64 * 64];    // row-major [key][d], XOR-swizzled 16B chunks
    __shared__ __align__(16) ushort vbufT[64 * 68];   // transposed [d][key], pad stride 68
    __shared__ float s_msk[SEQ];

    // bijective XCD swizzle: 16 q-tiles of one (b,h) stay on one XCD -> K/V L2 reuse
    const int bid = blockIdx.x;
    const int blk = (bid & 7) * 96 + (bid >> 3);
    const int qt = blk & 15;                  // SEQ/QBLK = 16
    const int h = (blk >> 4) % HEADS;
    const int b = blk / (16 * HEADS);
    const int i0 = qt * 64;
    const int tid = threadIdx.x;
    const int lane = tid & 63;
    const int w = tid >> 6;
    const int g = lane >> 4;   // 0..3
    const int c = lane & 15;

    float g0 = gammas[h];
    float gamma = -(fmaxf(g0, 0.f) + log1pf(expf(-fabsf(g0))));  // -softplus

    const ushort* khb = kh + ((size_t)b * HEADS + h) * SEQ * 64;
    const ushort* vhb = vh + ((size_t)b * HEADS + h) * SEQ * 64;
    const ushort* qhb = qh + ((size_t)b * HEADS + h) * SEQ * 64;

    for (int e = tid; e < SEQ; e += 256)
        s_msk[e] = (mask[b * SEQ + e] != 0) ? 1.f : 0.f;

    // Q B-fragments: row q = i0 + w*16 + c, k(d) = ks*32 + g*8 + e
    bf16x8 qf0, qf1;
    {
        const ushort* qrow = qhb + (size_t)(i0 + w * 16 + c) * 64 + g * 8;
        qf0 = *reinterpret_cast<const bf16x8*>(qrow);
        qf1 = *reinterpret_cast<const bf16x8*>(qrow + 32);
    }

    // ================= pass 1: raw denominator T per q-row =================
    float Tacc = 0.f;
    for (int chk = 0; chk < 16; ++chk) {
        const int j0 = chk * 64;
        __syncthreads();
#pragma unroll
        for (int it = 0; it < 2; ++it) {
            int gg = tid + it * 256;
            int row = gg >> 3, cc = gg & 7;
            uint4 val = *reinterpret_cast<const uint4*>(khb + (size_t)(j0 + row) * 64 + cc * 8);
            int boff = row * 128 + ((cc * 16) ^ ((row & 7) << 4));
            *reinterpret_cast<uint4*>((char*)kbuf + boff) = val;
        }
        __syncthreads();
#pragma unroll
        for (int m = 0; m < 4; ++m) {
            f32x4 acc = {0.f, 0.f, 0.f, 0.f};
            int row = m * 16 + c;
            int sw = (row & 7) << 4;
            bf16x8 kf0 = *reinterpret_cast<const bf16x8*>((char*)kbuf + row * 128 + ((g * 16) ^ sw));
            bf16x8 kf1 = *reinterpret_cast<const bf16x8*>((char*)kbuf + row * 128 + ((64 + g * 16) ^ sw));
            acc = __builtin_amdgcn_mfma_f32_16x16x32_bf16(kf0, qf0, acc, 0, 0, 0);
            acc = __builtin_amdgcn_mfma_f32_16x16x32_bf16(kf1, qf1, acc, 0, 0, 0);
#pragma unroll
            for (int r = 0; r < 4; ++r) {
                float mk = s_msk[j0 + m * 16 + g * 4 + r];
                Tacc += mk * __expf(acc[r] * 0.125f);
            }
        }
    }
    Tacc += __shfl_xor(Tacc, 16, 64);
    Tacc += __shfl_xor(Tacc, 32, 64);
    const float T = Tacc;
    const float invT = (T > 0.f) ? 1.f / T : 0.f;

    // ================= pass 2: cum, effect, second softmax, PV =================
    f32x4 ctx0 = {0,0,0,0}, ctx1 = {0,0,0,0}, ctx2 = {0,0,0,0}, ctx3 = {0,0,0,0};
    float l2acc = 0.f;
    float base = 0.f;
    const float iq = (float)(i0 + w * 16 + c);

    for (int chk = 0; chk < 16; ++chk) {
        const int j0 = chk * 64;
        __syncthreads();
#pragma unroll
        for (int it = 0; it < 2; ++it) {
            int gg = tid + it * 256;
            int row = gg >> 3, cc = gg & 7;       // row = key-in-tile, cc*8 = d base
            const size_t goff = (size_t)(j0 + row) * 64 + cc * 8;
            uint4 kval = *reinterpret_cast<const uint4*>(khb + goff);
            int boff = row * 128 + ((cc * 16) ^ ((row & 7) << 4));
            *reinterpret_cast<uint4*>((char*)kbuf + boff) = kval;
            uint4 vval = *reinterpret_cast<const uint4*>(vhb + goff);
            ushort hw8[8];
            hw8[0] = (ushort)(vval.x & 0xffff); hw8[1] = (ushort)(vval.x >> 16);
            hw8[2] = (ushort)(vval.y & 0xffff); hw8[3] = (ushort)(vval.y >> 16);
            hw8[4] = (ushort)(vval.z & 0xffff); hw8[5] = (ushort)(vval.z >> 16);
            hw8[6] = (ushort)(vval.w & 0xffff); hw8[7] = (ushort)(vval.w >> 16);
#pragma unroll
            for (int q = 0; q < 8; ++q) {
                int dd = q ^ (row & 7);           // rotate store order: spread banks
                vbufT[(cc * 8 + dd) * 68 + row] = hw8[dd];
            }
        }
        __syncthreads();
#pragma unroll
        for (int m = 0; m < 4; ++m) {
            f32x4 acc = {0.f, 0.f, 0.f, 0.f};
            int row = m * 16 + c;
            int sw = (row & 7) << 4;
            bf16x8 kf0 = *reinterpret_cast<const bf16x8*>((char*)kbuf + row * 128 + ((g * 16) ^ sw));
            bf16x8 kf1 = *reinterpret_cast<const bf16x8*>((char*)kbuf + row * 128 + ((64 + g * 16) ^ sw));
            acc = __builtin_amdgcn_mfma_f32_16x16x32_bf16(kf0, qf0, acc, 0, 0, 0);
            acc = __builtin_amdgcn_mfma_f32_16x16x32_bf16(kf1, qf1, acc, 0, 0, 0);

            float e[4], s[4], mk[4], incl[4];
            float li = 0.f;
#pragma unroll
            for (int r = 0; r < 4; ++r) {
                mk[r] = s_msk[j0 + m * 16 + g * 4 + r];
                s[r] = acc[r] * 0.125f;
                e[r] = mk[r] * __expf(s[r]);
                li += e[r];
                incl[r] = li;
            }
            // inclusive scan over the 4 key-groups g (keys m*16 + g*4 + r)
            float gs = li;
            float up = __shfl_up(gs, 16, 64); if (g >= 1) gs += up;
            up = __shfl_up(gs, 32, 64); if (g >= 2) gs += up;
            float gexcl = gs - li;
            float ttot = __shfl(gs, 48 + c, 64);   // tile total from g=3, same q

            float p2[4];
#pragma unroll
            for (int r = 0; r < 4; ++r) {
                float cum = base + gexcl + incl[r];
                float rem = fmaxf((T - cum) * invT, 0.f);
                float jf = (float)(j0 + m * 16 + g * 4 + r);
                float pos = fabsf(iq - jf);
                float dist = sqrtf(rem * pos);
                float eff = fminf(fmaxf(__expf(dist * gamma), 1e-5f), 1e5f);
                float s2 = (mk[r] != 0.f) ? s[r] * eff : -1e8f;
                p2[r] = __expf(s2);
                l2acc += p2[r];
            }
            base += ttot;

            bf16x4 pa;
            pa[0] = (short)f2bf(p2[0]); pa[1] = (short)f2bf(p2[1]);
            pa[2] = (short)f2bf(p2[2]); pa[3] = (short)f2bf(p2[3]);

            // B-frag: lane (g,c) needs V[16m + g*4 + e][16t + c] -> contiguous in vbufT
            const int vo = 16 * m + 4 * g;
            bf16x4 v0 = *reinterpret_cast<const bf16x4*>(&vbufT[(c +  0) * 68 + vo]);
            bf16x4 v1 = *reinterpret_cast<const bf16x4*>(&vbufT[(c + 16) * 68 + vo]);
            bf16x4 v2 = *reinterpret_cast<const bf16x4*>(&vbufT[(c + 32) * 68 + vo]);
            bf16x4 v3 = *reinterpret_cast<const bf16x4*>(&vbufT[(c + 48) * 68 + vo]);
            mfma16(ctx0, pa, v0);
            mfma16(ctx1, pa, v1);
            mfma16(ctx2, pa, v2);
            mfma16(ctx3, pa, v3);
        }
    }
    l2acc += __shfl_xor(l2acc, 16, 64);
    l2acc += __shfl_xor(l2acc, 32, 64);
    const float invl2 = 1.f / l2acc;

#pragma unroll
    for (int r = 0; r < 4; ++r) {
        float inv_r = __shfl(invl2, g * 4 + r, 64);   // stats live at lanes with (lane&15)==q
        int qrow = i0 + w * 16 + g * 4 + r;
        float* orow = out + ((size_t)b * SEQ + qrow) * (2 * ALLH) + h * DHEAD;
        orow[c +  0] = ctx0[r] * inv_r;
        orow[c + 16] = ctx1[r] * inv_r;
        orow[c + 32] = ctx2[r] * inv_r;
        orow[c + 48] = ctx3[r] * inv_r;
    }
}

// ---------------- launch ----------------
extern "C" void kernel_launch(void* const* d_in, const int* in_sizes, int n_in,
                              void* d_out, int out_size, void* d_ws, size_t ws_size,
                              hipStream_t stream) {
    const float* Q = (const float*)d_in[0];
    const float* Kin = (const float*)d_in[1];
    const float* V = (const float*)d_in[2];
    const float* Wq = (const float*)d_in[3];
    const float* Wk = (const float*)d_in[4];
    const float* Wv = (const float*)d_in[5];
    const float* dw = (const float*)d_in[6];
    const float* pw = (const float*)d_in[7];
    const float* sep_bias = (const float*)d_in[8];
    const float* Wck = (const float*)d_in[9];
    const float* bck = (const float*)d_in[10];
    const float* Wco = (const float*)d_in[11];
    const float* bco = (const float*)d_in[12];
    const float* gammas = (const float*)d_in[13];
    const int* mask = (const int*)d_in[14];
    float* out = (float*)d_out;
    float* ws = (float*)d_ws;

    const size_t NP = (size_t)MROWS * ALLH;        // 3145728
    const size_t WSZ = (size_t)ALLH * HID;         // 294912
    float* qb   = ws;                              // f32 q (spankern)
    float* cob  = qb + NP;
    float* kcb  = cob + NP;
    float* yb   = kcb + NP;                        // MROWS*HID f32
    float* kern = yb + (size_t)MROWS * HID;        // MROWS*54
    ushort* qh  = (ushort*)(kern + (size_t)MROWS * HEADS * KS);
    ushort* khm = qh + NP;
    ushort* vhm = khm + NP;
    ushort* WqT = vhm + NP;                        // [384,768] bf16 each
    ushort* WkT = WqT + WSZ;
    ushort* WvT = WkT + WSZ;
    ushort* WcoT = WvT + WSZ;
    ushort* pwT = WcoT + WSZ;

    // 1. depthwise conv on K + weight conversion (independent)
    dconv_kernel<<<(MROWS * (HID / 4) + 255) / 256, 256, 0, stream>>>(Kin, dw, yb);
    wcvt_kernel<<<dim3(24, 12, 4), 256, 0, stream>>>(Wq, Wk, Wv, Wco, WqT, WkT, WvT, WcoT);
    pwcvt_kernel<<<(ALLH * HID + 255) / 256, 256, 0, stream>>>(pw, pwT);

    // 2. projection GEMMs (bf16 MFMA, f32 A converted on load)
    gemm_mfma<1, false><<<768, 256, 0, stream>>>(Q, WqT, nullptr, qb, qh);
    gemm_mfma<2, false><<<768, 256, 0, stream>>>(Kin, WkT, nullptr, nullptr, khm);
    gemm_mfma<2, false><<<768, 256, 0, stream>>>(V, WvT, nullptr, nullptr, vhm);
    gemm_mfma<0, true><<<768, 256, 0, stream>>>(V, WcoT, bco, cob, nullptr);
    gemm_mfma<0, true><<<768, 256, 0, stream>>>(yb, pwT, sep_bias, kcb, nullptr);

    // 3. span-dynamic-conv kernel weights + softmax
    spankern_kernel<<<MROWS / 4, 256, 0, stream>>>(kcb, qb, Wck, bck, kern);

    // 4. conv branch output (channels 384..767)
    convout_kernel<<<(MROWS * (ALLH / 4) + 255) / 256, 256, 0, stream>>>(cob, kern, out);

    // 5. fused monotonic attention via MFMA (channels 0..383)
    attn_mfma<<<BATCH * HEADS * (SEQ / 64), 256, 0, stream>>>(qh, khm, vhm, mask, gammas, out);
}

// Round 10
// 305.452 us; speedup vs baseline: 5.1482x; 1.1111x over previous
//
#include <hip/hip_runtime.h>
#include <math.h>

#define BATCH 8
#define SEQ   1024
#define HID   768
#define HEADS 6
#define DHEAD 64
#define ALLH  384   // HEADS*DHEAD
#define KS    9
#define PADC  4
#define MROWS (BATCH*SEQ)  // 8192

typedef __attribute__((ext_vector_type(8))) short bf16x8;
typedef __attribute__((ext_vector_type(4))) short bf16x4;
typedef __attribute__((ext_vector_type(4))) float f32x4;

__device__ __forceinline__ ushort f2bf(float x) {   // RTN-even f32 -> bf16 bits
    unsigned u = __float_as_uint(x);
    unsigned r = (u + 0x7FFFu + ((u >> 16) & 1u)) >> 16;
    return (ushort)r;
}
__device__ __forceinline__ unsigned pk2(float a, float b) {
    return (unsigned)f2bf(a) | ((unsigned)f2bf(b) << 16);
}
// TRANS ops via compiler-known paths (hazard handling)
__device__ __forceinline__ float fexp2(float x) {
#if __has_builtin(__builtin_amdgcn_exp2f)
    return __builtin_amdgcn_exp2f(x);
#else
    return exp2f(x);
#endif
}
__device__ __forceinline__ float fsqrt(float x) {
#if __has_builtin(__builtin_amdgcn_sqrtf)
    return __builtin_amdgcn_sqrtf(x);
#else
    return __sqrtf(x);
#endif
}
__device__ __forceinline__ unsigned cvtpk(float a, float b) {  // 2 bf16 in 1 instr (RNE, non-trans)
    unsigned r; asm("v_cvt_pk_bf16_f32 %0, %1, %2" : "=v"(r) : "v"(a), "v"(b)); return r;
}

__device__ __forceinline__ void mfma16(f32x4& c4, bf16x4 a, bf16x4 b) {
#if __has_builtin(__builtin_amdgcn_mfma_f32_16x16x16bf16_1k)
    c4 = __builtin_amdgcn_mfma_f32_16x16x16bf16_1k(a, b, c4, 0, 0, 0);
#else
    asm volatile("v_mfma_f32_16x16x16_bf16 %0, %1, %2, %0" : "+v"(c4) : "v"(a), "v"(b));
#endif
}

// ---------------- f32 -> bf16 pre-convert (Q, Kin, V) ----------------
__global__ __launch_bounds__(256) void precvt_kernel(const float* __restrict__ Q,
                                                     const float* __restrict__ K,
                                                     const float* __restrict__ V,
                                                     ushort* __restrict__ Qb,
                                                     ushort* __restrict__ Kb,
                                                     ushort* __restrict__ Vb) {
    int z = blockIdx.z;
    const float* src = z == 0 ? Q : z == 1 ? K : V;
    ushort* dst = z == 0 ? Qb : z == 1 ? Kb : Vb;
    size_t i = ((size_t)blockIdx.x * 256 + threadIdx.x) * 8;
    const float4 f0 = *reinterpret_cast<const float4*>(src + i);
    const float4 f1 = *reinterpret_cast<const float4*>(src + i + 4);
    uint4 p;
    p.x = pk2(f0.x, f0.y); p.y = pk2(f0.z, f0.w);
    p.z = pk2(f1.x, f1.y); p.w = pk2(f1.z, f1.w);
    *reinterpret_cast<uint4*>(dst + i) = p;
}

// ---------------- depthwise conv on K -> bf16 directly ----------------
__global__ __launch_bounds__(256) void dconv_kernel(const float* __restrict__ Kin,
                                                    const float* __restrict__ dw,
                                                    ushort* __restrict__ y) {
    int idx = blockIdx.x * 256 + threadIdx.x;
    if (idx >= MROWS * (HID / 4)) return;
    int c4 = idx % (HID / 4);
    int s = (idx / (HID / 4)) % SEQ;
    int b = idx / ((HID / 4) * SEQ);
    int c = c4 * 4;
    float4 acc = {0.f, 0.f, 0.f, 0.f};
#pragma unroll
    for (int t = 0; t < KS; ++t) {
        int sj = s + t - PADC;
        if (sj >= 0 && sj < SEQ) {
            const float4 kv = *reinterpret_cast<const float4*>(&Kin[((size_t)b * SEQ + sj) * HID + c]);
            acc.x += kv.x * dw[(c + 0) * KS + t];
            acc.y += kv.y * dw[(c + 1) * KS + t];
            acc.z += kv.z * dw[(c + 2) * KS + t];
            acc.w += kv.w * dw[(c + 3) * KS + t];
        }
    }
    uint2 o;
    o.x = pk2(acc.x, acc.y); o.y = pk2(acc.z, acc.w);
    *reinterpret_cast<uint2*>(&y[((size_t)b * SEQ + s) * HID + c]) = o;
}

// ---------------- weight transpose-convert: W[768,384] f32 -> Wt[384,768] bf16 ----------------
__global__ __launch_bounds__(256) void wcvt_kernel(const float* __restrict__ W0, const float* __restrict__ W1,
                                                   const float* __restrict__ W2, const float* __restrict__ W3,
                                                   ushort* __restrict__ O0, ushort* __restrict__ O1,
                                                   ushort* __restrict__ O2, ushort* __restrict__ O3) {
    __shared__ float t[32][33];
    int wsel = blockIdx.z;
    const float* W = wsel == 0 ? W0 : wsel == 1 ? W1 : wsel == 2 ? W2 : W3;
    ushort* O = wsel == 0 ? O0 : wsel == 1 ? O1 : wsel == 2 ? O2 : O3;
    int kt = blockIdx.x * 32;
    int nt = blockIdx.y * 32;
    int tx = threadIdx.x & 31, ty = threadIdx.x >> 5;
#pragma unroll
    for (int i = 0; i < 4; ++i)
        t[ty + i * 8][tx] = W[(size_t)(kt + ty + i * 8) * ALLH + nt + tx];
    __syncthreads();
#pragma unroll
    for (int i = 0; i < 4; ++i)
        O[(size_t)(nt + ty + i * 8) * HID + kt + tx] = f2bf(t[tx][ty + i * 8]);
}

// ---------------- pw convert (already [N=384, K=768]) ----------------
__global__ __launch_bounds__(256) void pwcvt_kernel(const float* __restrict__ pw, ushort* __restrict__ pwb) {
    int i = blockIdx.x * 256 + threadIdx.x;
    if (i < ALLH * HID) pwb[i] = f2bf(pw[i]);
}

// ---------------- bf16 MFMA GEMM: C[8192,384] = A[8192,768]bf16 @ Bt[384,768]^T ----------------
// BMODE: 0 = f32 only, 1 = f32 + qh plain head-major, 2 = khm swizzled tiles, 3 = vhm transposed+swizzled tiles
template <int BMODE, bool HAS_BIAS>
__global__ __launch_bounds__(256) void gemm_mfma(const ushort* __restrict__ A,
                                                 const ushort* __restrict__ Bt,
                                                 const float* __restrict__ bias,
                                                 float* __restrict__ C,
                                                 ushort* __restrict__ Chm) {
    __shared__ __align__(16) ushort As[64 * 64];
    __shared__ __align__(16) ushort Bs[64 * 64];

    const int bid = blockIdx.x;
    const int swz = (bid & 7) * 96 + (bid >> 3);   // bijective: 768 = 8*96
    const int n0 = (swz % 6) * 64;
    const int m0 = (swz / 6) * 64;

    const int tid = threadIdx.x;
    const int lane = tid & 63;
    const int w = tid >> 6;
    const int g = lane >> 4;
    const int c = lane & 15;

    f32x4 acc[4] = {{0,0,0,0},{0,0,0,0},{0,0,0,0},{0,0,0,0}};

    for (int k0 = 0; k0 < HID; k0 += 64) {
        __syncthreads();
#pragma unroll
        for (int it = 0; it < 2; ++it) {
            int e = tid + it * 256;
            int row = e >> 3;
            int c8 = (e & 7) * 8;
            int boff = row * 128 + ((c8 * 2) ^ ((row & 7) << 4));
            const uint4 av = *reinterpret_cast<const uint4*>(&A[(size_t)(m0 + row) * HID + k0 + c8]);
            *reinterpret_cast<uint4*>((char*)As + boff) = av;
            const uint4 bv = *reinterpret_cast<const uint4*>(&Bt[(size_t)(n0 + row) * HID + k0 + c8]);
            *reinterpret_cast<uint4*>((char*)Bs + boff) = bv;
        }
        __syncthreads();

        const int arow = w * 16 + c;
        const int asw = (arow & 7) << 4;
        bf16x8 af0 = *reinterpret_cast<const bf16x8*>((char*)As + arow * 128 + ((g * 16) ^ asw));
        bf16x8 af1 = *reinterpret_cast<const bf16x8*>((char*)As + arow * 128 + ((64 + g * 16) ^ asw));
#pragma unroll
        for (int nq = 0; nq < 4; ++nq) {
            const int brow = nq * 16 + c;
            const int bsw = (brow & 7) << 4;
            bf16x8 bf0 = *reinterpret_cast<const bf16x8*>((char*)Bs + brow * 128 + ((g * 16) ^ bsw));
            bf16x8 bf1 = *reinterpret_cast<const bf16x8*>((char*)Bs + brow * 128 + ((64 + g * 16) ^ bsw));
            acc[nq] = __builtin_amdgcn_mfma_f32_16x16x32_bf16(af0, bf0, acc[nq], 0, 0, 0);
            acc[nq] = __builtin_amdgcn_mfma_f32_16x16x32_bf16(af1, bf1, acc[nq], 0, 0, 0);
        }
    }

    if (BMODE == 3) {
        // V: transposed+swizzled 64x64 tiles [d-row][key-col], tile = (bb*6+head)*16 + st
        const int head = n0 >> 6;
        const int bb = m0 >> 10;
        const int st = (m0 & 1023) >> 6;
        char* tb = (char*)Chm + (((size_t)(bb * HEADS + head) * 16 + st) * 4096) * 2;
#pragma unroll
        for (int nq = 0; nq < 4; ++nq) {
            const int d = nq * 16 + c;
            unsigned off = (unsigned)d * 128 + (((unsigned)(32 * w + 8 * g)) ^ ((d & 7) << 4));
            uint2 vv;
            vv.x = pk2(acc[nq][0], acc[nq][1]);
            vv.y = pk2(acc[nq][2], acc[nq][3]);
            *reinterpret_cast<uint2*>(tb + off) = vv;
        }
        return;
    }

#pragma unroll
    for (int nq = 0; nq < 4; ++nq) {
        const int n = n0 + nq * 16 + c;
        const float bv = HAS_BIAS ? bias[n] : 0.f;
#pragma unroll
        for (int r = 0; r < 4; ++r) {
            const int m = m0 + w * 16 + g * 4 + r;
            float v = acc[nq][r] + bv;
            if (BMODE == 0 || BMODE == 1) C[(size_t)m * ALLH + n] = v;
            if (BMODE == 1) {
                int bb = m >> 10, s = m & 1023;
                int head = n >> 6, d = n & 63;
                Chm[(((size_t)bb * HEADS + head) * SEQ + s) * 64 + d] = f2bf(v);
            }
            if (BMODE == 2) {
                int bb = m >> 10, s = m & 1023;
                int head = n >> 6, d = n & 63;
                char* tb = (char*)Chm + (((size_t)(bb * HEADS + head) * 16 + (s >> 6)) * 4096) * 2;
                unsigned off = (unsigned)(s & 63) * 128 + (((unsigned)(d * 2)) ^ ((s & 7) << 4));
                *reinterpret_cast<ushort*>(tb + off) = f2bf(v);
            }
        }
    }
}

// ---------------- span kernel ----------------
__global__ __launch_bounds__(256) void spankern_kernel(const float* __restrict__ keyconv,
                                                       const float* __restrict__ q,
                                                       const float* __restrict__ Wck,
                                                       const float* __restrict__ bck,
                                                       float* __restrict__ kern_sm) {
    __shared__ float ca[4][ALLH];
    __shared__ float kv[4][64];
    int row0 = blockIdx.x * 4;
    int tid = threadIdx.x;
    int r = tid >> 6;
    int lane = tid & 63;
    int row = row0 + r;
    for (int e = lane; e < ALLH; e += 64) {
        size_t off = (size_t)row * ALLH + e;
        ca[r][e] = keyconv[off] * q[off];
    }
    __syncthreads();
    float val = 0.f;
    if (lane < HEADS * KS) {
        for (int kidx = 0; kidx < ALLH; ++kidx)
            val += ca[r][kidx] * Wck[kidx * (HEADS * KS) + lane];
        val += bck[lane];
    }
    kv[r][lane] = val;
    __syncthreads();
    if (lane < HEADS) {
        float mx = -INFINITY;
#pragma unroll
        for (int t = 0; t < KS; ++t) mx = fmaxf(mx, kv[r][lane * KS + t]);
        float e[KS];
        float sum = 0.f;
#pragma unroll
        for (int t = 0; t < KS; ++t) {
            e[t] = expf(kv[r][lane * KS + t] - mx);
            sum += e[t];
        }
        float inv = 1.f / sum;
#pragma unroll
        for (int t = 0; t < KS; ++t)
            kern_sm[((size_t)row * HEADS + lane) * KS + t] = e[t] * inv;
    }
}

// ---------------- conv_out ----------------
__global__ __launch_bounds__(256) void convout_kernel(const float* __restrict__ co,
                                                      const float* __restrict__ kern_sm,
                                                      float* __restrict__ out) {
    int idx = blockIdx.x * 256 + threadIdx.x;
    if (idx >= MROWS * (ALLH / 4)) return;
    int c4 = idx % (ALLH / 4);
    int s = (idx / (ALLH / 4)) % SEQ;
    int b = idx / ((ALLH / 4) * SEQ);
    int c = c4 * 4;
    int h = c >> 6;
    const float* ks = &kern_sm[(((size_t)b * SEQ + s) * HEADS + h) * KS];
    float kt[KS];
#pragma unroll
    for (int t = 0; t < KS; ++t) kt[t] = ks[t];
    float4 acc = {0.f, 0.f, 0.f, 0.f};
#pragma unroll
    for (int t = 0; t < KS; ++t) {
        int sj = s + t - PADC;
        if (sj >= 0 && sj < SEQ) {
            const float4 cv = *reinterpret_cast<const float4*>(&co[((size_t)b * SEQ + sj) * ALLH + c]);
            acc.x += cv.x * kt[t];
            acc.y += cv.y * kt[t];
            acc.z += cv.z * kt[t];
            acc.w += cv.w * kt[t];
        }
    }
    *reinterpret_cast<float4*>(&out[((size_t)b * SEQ + s) * (2 * ALLH) + ALLH + c]) = acc;
}

// ---------------- fused monotonic attention (MFMA, pre-swizzled K/V tiles) ----------------
__global__ __launch_bounds__(256) void attn_mfma(const ushort* __restrict__ qh,
                                                 const ushort* __restrict__ kh,
                                                 const ushort* __restrict__ vh,
                                                 const int* __restrict__ mask,
                                                 const float* __restrict__ gammas,
                                                 float* __restrict__ out) {
    __shared__ __align__(16) ushort kbuf[64 * 64];   // swizzled [key][d] tile (copied verbatim)
    __shared__ __align__(16) ushort vbuf[64 * 64];   // transposed+swizzled [d][key] tile
    __shared__ float s_msk[SEQ];

    const int bid = blockIdx.x;
    const int blk = (bid & 7) * 96 + (bid >> 3);
    const int qt = blk & 15;
    const int h = (blk >> 4) % HEADS;
    const int b = blk / (16 * HEADS);
    const int i0 = qt * 64;
    const int tid = threadIdx.x;
    const int lane = tid & 63;
    const int w = tid >> 6;
    const int g = lane >> 4;
    const int c = lane & 15;

    const float LOG2E = 1.44269504f;
    float g0 = gammas[h];
    float gamma2 = -(fmaxf(g0, 0.f) + log1pf(expf(-fabsf(g0)))) * LOG2E;  // -softplus * log2e
    const float SLOG2 = 0.125f * LOG2E;

    const ushort* ktiles = kh + ((size_t)(b * HEADS + h) * 16) * 4096;
    const ushort* vtiles = vh + ((size_t)(b * HEADS + h) * 16) * 4096;
    const ushort* qhb = qh + ((size_t)b * HEADS + h) * SEQ * 64;

    for (int e = tid; e < SEQ; e += 256)
        s_msk[e] = (mask[b * SEQ + e] != 0) ? 1.f : 0.f;

    // Q B-fragments
    bf16x8 qf0, qf1;
    {
        const ushort* qrow = qhb + (size_t)(i0 + w * 16 + c) * 64 + g * 8;
        qf0 = *reinterpret_cast<const bf16x8*>(qrow);
        qf1 = *reinterpret_cast<const bf16x8*>(qrow + 32);
    }

    // ================= pass 1: raw denominator T =================
    float Tacc = 0.f;
    for (int chk = 0; chk < 16; ++chk) {
        __syncthreads();
        const ushort* ktp = ktiles + chk * 4096;
#pragma unroll
        for (int it = 0; it < 2; ++it) {
            int e16 = (tid + it * 256) * 16;
            *reinterpret_cast<uint4*>((char*)kbuf + e16) =
                *reinterpret_cast<const uint4*>((const char*)ktp + e16);
        }
        __syncthreads();
        const int j0 = chk * 64;
#pragma unroll
        for (int m = 0; m < 4; ++m) {
            f32x4 acc = {0.f, 0.f, 0.f, 0.f};
            int row = m * 16 + c;
            int sw = (row & 7) << 4;
            bf16x8 kf0 = *reinterpret_cast<const bf16x8*>((char*)kbuf + row * 128 + ((g * 16) ^ sw));
            bf16x8 kf1 = *reinterpret_cast<const bf16x8*>((char*)kbuf + row * 128 + ((64 + g * 16) ^ sw));
            acc = __builtin_amdgcn_mfma_f32_16x16x32_bf16(kf0, qf0, acc, 0, 0, 0);
            acc = __builtin_amdgcn_mfma_f32_16x16x32_bf16(kf1, qf1, acc, 0, 0, 0);
#pragma unroll
            for (int r = 0; r < 4; ++r) {
                float mk = s_msk[j0 + m * 16 + g * 4 + r];
                Tacc += mk * fexp2(acc[r] * SLOG2);
            }
        }
    }
    Tacc += __shfl_xor(Tacc, 16, 64);
    Tacc += __shfl_xor(Tacc, 32, 64);
    const float T = Tacc;
    const float invT = (T > 0.f) ? 1.f / T : 0.f;

    // ================= pass 2: cum, effect, second softmax, PV =================
    f32x4 ctx0 = {0,0,0,0}, ctx1 = {0,0,0,0}, ctx2 = {0,0,0,0}, ctx3 = {0,0,0,0};
    float l2acc = 0.f;
    float base = 0.f;
    const float iq = (float)(i0 + w * 16 + c);
    const unsigned vx = (unsigned)((c & 7) << 4);    // lane-const read swizzle

    for (int chk = 0; chk < 16; ++chk) {
        __syncthreads();
        const ushort* ktp = ktiles + chk * 4096;
        const ushort* vtp = vtiles + chk * 4096;
#pragma unroll
        for (int it = 0; it < 2; ++it) {
            int e16 = (tid + it * 256) * 16;
            *reinterpret_cast<uint4*>((char*)kbuf + e16) =
                *reinterpret_cast<const uint4*>((const char*)ktp + e16);
            *reinterpret_cast<uint4*>((char*)vbuf + e16) =
                *reinterpret_cast<const uint4*>((const char*)vtp + e16);
        }
        __syncthreads();
        const int j0 = chk * 64;
#pragma unroll
        for (int m = 0; m < 4; ++m) {
            f32x4 acc = {0.f, 0.f, 0.f, 0.f};
            int row = m * 16 + c;
            int sw = (row & 7) << 4;
            bf16x8 kf0 = *reinterpret_cast<const bf16x8*>((char*)kbuf + row * 128 + ((g * 16) ^ sw));
            bf16x8 kf1 = *reinterpret_cast<const bf16x8*>((char*)kbuf + row * 128 + ((64 + g * 16) ^ sw));
            acc = __builtin_amdgcn_mfma_f32_16x16x32_bf16(kf0, qf0, acc, 0, 0, 0);
            acc = __builtin_amdgcn_mfma_f32_16x16x32_bf16(kf1, qf1, acc, 0, 0, 0);

            float sl[4], mk[4], incl[4];
            float li = 0.f;
#pragma unroll
            for (int r = 0; r < 4; ++r) {
                mk[r] = s_msk[j0 + m * 16 + g * 4 + r];
                sl[r] = acc[r] * SLOG2;                 // score in log2 units
                float e = mk[r] * fexp2(sl[r]);
                li += e;
                incl[r] = li;
            }
            float gs = li;
            float up = __shfl_up(gs, 16, 64); if (g >= 1) gs += up;
            up = __shfl_up(gs, 32, 64); if (g >= 2) gs += up;
            float gexcl = gs - li;
            float ttot = __shfl(gs, 48 + c, 64);

            const float dbase = iq - (float)(j0 + m * 16 + g * 4);
            float p2[4];
#pragma unroll
            for (int r = 0; r < 4; ++r) {
                float cum = base + gexcl + incl[r];
                float rem = fmaxf(1.0f - cum * invT, 0.f);
                float pos = fabsf(dbase - (float)r);
                float dist = fsqrt(rem * pos);
                float eff = fmaxf(fexp2(dist * gamma2), 1e-5f);  // gamma2<0, dist>=0 -> eff<=1
                p2[r] = mk[r] * fexp2(sl[r] * eff);
                l2acc += p2[r];
            }
            base += ttot;

            union { uint2 u; bf16x4 v; } pu;
            pu.u.x = cvtpk(p2[0], p2[1]);
            pu.u.y = cvtpk(p2[2], p2[3]);
            bf16x4 pa = pu.v;

            const unsigned cb = ((unsigned)(32 * m + 8 * g)) ^ vx;
#pragma unroll
            for (int t = 0; t < 4; ++t) {
                bf16x4 vfrag = *reinterpret_cast<const bf16x4*>((char*)vbuf + (unsigned)(c + 16 * t) * 128 + cb);
                if (t == 0) mfma16(ctx0, pa, vfrag);
                else if (t == 1) mfma16(ctx1, pa, vfrag);
                else if (t == 2) mfma16(ctx2, pa, vfrag);
                else mfma16(ctx3, pa, vfrag);
            }
        }
    }
    l2acc += __shfl_xor(l2acc, 16, 64);
    l2acc += __shfl_xor(l2acc, 32, 64);
    const float invl2 = 1.f / l2acc;

#pragma unroll
    for (int r = 0; r < 4; ++r) {
        float inv_r = __shfl(invl2, g * 4 + r, 64);
        int qrow = i0 + w * 16 + g * 4 + r;
        float* orow = out + ((size_t)b * SEQ + qrow) * (2 * ALLH) + h * DHEAD;
        orow[c +  0] = ctx0[r] * inv_r;
        orow[c + 16] = ctx1[r] * inv_r;
        orow[c + 32] = ctx2[r] * inv_r;
        orow[c + 48] = ctx3[r] * inv_r;
    }
}

// ---------------- launch ----------------
extern "C" void kernel_launch(void* const* d_in, const int* in_sizes, int n_in,
                              void* d_out, int out_size, void* d_ws, size_t ws_size,
                              hipStream_t stream) {
    const float* Q = (const float*)d_in[0];
    const float* Kin = (const float*)d_in[1];
    const float* V = (const float*)d_in[2];
    const float* Wq = (const float*)d_in[3];
    const float* Wk = (const float*)d_in[4];
    const float* Wv = (const float*)d_in[5];
    const float* dw = (const float*)d_in[6];
    const float* pw = (const float*)d_in[7];
    const float* sep_bias = (const float*)d_in[8];
    const float* Wck = (const float*)d_in[9];
    const float* bck = (const float*)d_in[10];
    const float* Wco = (const float*)d_in[11];
    const float* bco = (const float*)d_in[12];
    const float* gammas = (const float*)d_in[13];
    const int* mask = (const int*)d_in[14];
    float* out = (float*)d_out;
    float* ws = (float*)d_ws;

    const size_t NP = (size_t)MROWS * ALLH;        // 3145728
    const size_t WSZ = (size_t)ALLH * HID;         // 294912
    float* qb   = ws;                              // f32 q (spankern)
    float* cob  = qb + NP;
    float* kcb  = cob + NP;
    float* kern = kcb + NP;                        // 8192*54
    ushort* qh  = (ushort*)(kern + (size_t)MROWS * HEADS * KS);
    ushort* khm = qh + NP;                         // swizzled K tiles
    ushort* vhm = khm + NP;                        // transposed+swizzled V tiles
    ushort* Vbf = vhm + NP;                        // V bf16: MROWS*HID = 2*NP ushorts!
    ushort* ybf = Vbf + 2 * NP;                    // FIX R10: was Vbf+NP -> V batches 4-7 corrupted
    ushort* WqT = ybf + (size_t)MROWS * HID;
    ushort* WkT = WqT + WSZ;
    ushort* WvT = WkT + WSZ;
    ushort* WcoT = WvT + WSZ;
    ushort* pwT = WcoT + WSZ;
    ushort* Qbf = (ushort*)kcb;                    // alias: 2*NP ushorts = NP floats, exact fit
    ushort* Kbf = (ushort*)cob;                    // alias: ditto; cob written after K-GEMM read

    // 1. dtype conversions + depthwise conv
    precvt_kernel<<<dim3(MROWS * HID / (256 * 8), 1, 3), 256, 0, stream>>>(Q, Kin, V, Qbf, Kbf, Vbf);
    dconv_kernel<<<(MROWS * (HID / 4) + 255) / 256, 256, 0, stream>>>(Kin, dw, ybf);
    wcvt_kernel<<<dim3(24, 12, 4), 256, 0, stream>>>(Wq, Wk, Wv, Wco, WqT, WkT, WvT, WcoT);
    pwcvt_kernel<<<(ALLH * HID + 255) / 256, 256, 0, stream>>>(pw, pwT);

    // 2. projection GEMMs (all-bf16 staging)
    gemm_mfma<1, false><<<768, 256, 0, stream>>>(Qbf, WqT, nullptr, qb, qh);
    gemm_mfma<2, false><<<768, 256, 0, stream>>>(Kbf, WkT, nullptr, nullptr, khm);
    gemm_mfma<3, false><<<768, 256, 0, stream>>>(Vbf, WvT, nullptr, nullptr, vhm);
    gemm_mfma<0, true><<<768, 256, 0, stream>>>(Vbf, WcoT, bco, cob, nullptr);
    gemm_mfma<0, true><<<768, 256, 0, stream>>>(ybf, pwT, sep_bias, kcb, nullptr);

    // 3. span-dynamic-conv kernel weights + softmax
    spankern_kernel<<<MROWS / 4, 256, 0, stream>>>(kcb, qb, Wck, bck, kern);

    // 4. conv branch output (channels 384..767)
    convout_kernel<<<(MROWS * (ALLH / 4) + 255) / 256, 256, 0, stream>>>(cob, kern, out);

    // 5. fused monotonic attention (channels 0..383)
    attn_mfma<<<BATCH * HEADS * (SEQ / 64), 256, 0, stream>>>(qh, khm, vhm, mask, gammas, out);
}

// Round 12
// 302.125 us; speedup vs baseline: 5.2049x; 1.0110x over previous
//
#include <hip/hip_runtime.h>
#include <math.h>

#define BATCH 8
#define SEQ   1024
#define HID   768
#define HEADS 6
#define DHEAD 64
#define ALLH  384   // HEADS*DHEAD
#define KS    9
#define PADC  4
#define MROWS (BATCH*SEQ)  // 8192

typedef __attribute__((ext_vector_type(8))) short bf16x8;
typedef __attribute__((ext_vector_type(4))) short bf16x4;
typedef __attribute__((ext_vector_type(4))) float f32x4;

__device__ __forceinline__ ushort f2bf(float x) {   // RTN-even f32 -> bf16 bits
    unsigned u = __float_as_uint(x);
    unsigned r = (u + 0x7FFFu + ((u >> 16) & 1u)) >> 16;
    return (ushort)r;
}
__device__ __forceinline__ unsigned pk2(float a, float b) {
    return (unsigned)f2bf(a) | ((unsigned)f2bf(b) << 16);
}
// TRANS ops via compiler-known paths (hazard handling) -- R7 lesson
__device__ __forceinline__ float fexp2(float x) {
#if __has_builtin(__builtin_amdgcn_exp2f)
    return __builtin_amdgcn_exp2f(x);
#else
    return exp2f(x);
#endif
}
__device__ __forceinline__ float fsqrt(float x) {
#if __has_builtin(__builtin_amdgcn_sqrtf)
    return __builtin_amdgcn_sqrtf(x);
#else
    return __sqrtf(x);
#endif
}
__device__ __forceinline__ unsigned cvtpk(float a, float b) {  // 2 bf16 in 1 instr (RNE, non-trans)
    unsigned r; asm("v_cvt_pk_bf16_f32 %0, %1, %2" : "=v"(r) : "v"(a), "v"(b)); return r;
}

__device__ __forceinline__ void mfma16(f32x4& c4, bf16x4 a, bf16x4 b) {
#if __has_builtin(__builtin_amdgcn_mfma_f32_16x16x16bf16_1k)
    c4 = __builtin_amdgcn_mfma_f32_16x16x16bf16_1k(a, b, c4, 0, 0, 0);
#else
    asm volatile("v_mfma_f32_16x16x16_bf16 %0, %1, %2, %0" : "+v"(c4) : "v"(a), "v"(b));
#endif
}

// ---------------- f32 -> bf16 pre-convert (V only) ----------------
__global__ __launch_bounds__(256) void precvt_kernel(const float* __restrict__ src,
                                                     ushort* __restrict__ dst) {
    size_t i = ((size_t)blockIdx.x * 256 + threadIdx.x) * 8;
    const float4 f0 = *reinterpret_cast<const float4*>(src + i);
    const float4 f1 = *reinterpret_cast<const float4*>(src + i + 4);
    uint4 p;
    p.x = pk2(f0.x, f0.y); p.y = pk2(f0.z, f0.w);
    p.z = pk2(f1.x, f1.y); p.w = pk2(f1.z, f1.w);
    *reinterpret_cast<uint4*>(dst + i) = p;
}

// ---------------- depthwise conv on K -> bf16 directly ----------------
__global__ __launch_bounds__(256) void dconv_kernel(const float* __restrict__ Kin,
                                                    const float* __restrict__ dw,
                                                    ushort* __restrict__ y) {
    int idx = blockIdx.x * 256 + threadIdx.x;
    if (idx >= MROWS * (HID / 4)) return;
    int c4 = idx % (HID / 4);
    int s = (idx / (HID / 4)) % SEQ;
    int b = idx / ((HID / 4) * SEQ);
    int c = c4 * 4;
    float4 acc = {0.f, 0.f, 0.f, 0.f};
#pragma unroll
    for (int t = 0; t < KS; ++t) {
        int sj = s + t - PADC;
        if (sj >= 0 && sj < SEQ) {
            const float4 kv = *reinterpret_cast<const float4*>(&Kin[((size_t)b * SEQ + sj) * HID + c]);
            acc.x += kv.x * dw[(c + 0) * KS + t];
            acc.y += kv.y * dw[(c + 1) * KS + t];
            acc.z += kv.z * dw[(c + 2) * KS + t];
            acc.w += kv.w * dw[(c + 3) * KS + t];
        }
    }
    uint2 o;
    o.x = pk2(acc.x, acc.y); o.y = pk2(acc.z, acc.w);
    *reinterpret_cast<uint2*>(&y[((size_t)b * SEQ + s) * HID + c]) = o;
}

// ---------------- weight transpose-convert: W[768,384] f32 -> Wt[384,768] bf16 ----------------
__global__ __launch_bounds__(256) void wcvt_kernel(const float* __restrict__ W0, const float* __restrict__ W1,
                                                   const float* __restrict__ W2, const float* __restrict__ W3,
                                                   ushort* __restrict__ O0, ushort* __restrict__ O1,
                                                   ushort* __restrict__ O2, ushort* __restrict__ O3) {
    __shared__ float t[32][33];
    int wsel = blockIdx.z;
    const float* W = wsel == 0 ? W0 : wsel == 1 ? W1 : wsel == 2 ? W2 : W3;
    ushort* O = wsel == 0 ? O0 : wsel == 1 ? O1 : wsel == 2 ? O2 : O3;
    int kt = blockIdx.x * 32;
    int nt = blockIdx.y * 32;
    int tx = threadIdx.x & 31, ty = threadIdx.x >> 5;
#pragma unroll
    for (int i = 0; i < 4; ++i)
        t[ty + i * 8][tx] = W[(size_t)(kt + ty + i * 8) * ALLH + nt + tx];
    __syncthreads();
#pragma unroll
    for (int i = 0; i < 4; ++i)
        O[(size_t)(nt + ty + i * 8) * HID + kt + tx] = f2bf(t[tx][ty + i * 8]);
}

// ---------------- pw convert (already [N=384, K=768]) ----------------
__global__ __launch_bounds__(256) void pwcvt_kernel(const float* __restrict__ pw, ushort* __restrict__ pwb) {
    int i = blockIdx.x * 256 + threadIdx.x;
    if (i < ALLH * HID) pwb[i] = f2bf(pw[i]);
}

// ---------------- bf16 MFMA GEMM, 1-phase (R10-proven loop) ----------------
// C[8192,384] = A[8192,768] @ Bt[384,768]^T. AF32: A is f32, converted during staging (R6-proven).
// BMODE: 0 = f32 only, 1 = f32 + qh plain head-major, 2 = khm swizzled tiles
template <int BMODE, bool HAS_BIAS, bool AF32>
__global__ __launch_bounds__(256) void gemm_mfma(const void* __restrict__ Ap,
                                                 const ushort* __restrict__ Bt,
                                                 const float* __restrict__ bias,
                                                 float* __restrict__ C,
                                                 ushort* __restrict__ Chm) {
    __shared__ __align__(16) ushort As[64 * 64];
    __shared__ __align__(16) ushort Bs[64 * 64];

    const int bid = blockIdx.x;
    const int swz = (bid & 7) * 96 + (bid >> 3);   // bijective: 768 = 8*96
    const int n0 = (swz % 6) * 64;
    const int m0 = (swz / 6) * 64;

    const int tid = threadIdx.x;
    const int lane = tid & 63;
    const int w = tid >> 6;
    const int g = lane >> 4;
    const int c = lane & 15;

    const ushort* Ab = (const ushort*)Ap;
    const float* Af = (const float*)Ap;

    f32x4 acc[4] = {{0,0,0,0},{0,0,0,0},{0,0,0,0},{0,0,0,0}};

    for (int k0 = 0; k0 < HID; k0 += 64) {
        __syncthreads();
#pragma unroll
        for (int it = 0; it < 2; ++it) {
            int e = tid + it * 256;
            int row = e >> 3;
            int c8 = (e & 7) * 8;
            int boff = row * 128 + ((c8 * 2) ^ ((row & 7) << 4));
            if (AF32) {
                const float4 f0 = *reinterpret_cast<const float4*>(&Af[(size_t)(m0 + row) * HID + k0 + c8]);
                const float4 f1 = *reinterpret_cast<const float4*>(&Af[(size_t)(m0 + row) * HID + k0 + c8 + 4]);
                uint4 p;
                p.x = pk2(f0.x, f0.y); p.y = pk2(f0.z, f0.w);
                p.z = pk2(f1.x, f1.y); p.w = pk2(f1.z, f1.w);
                *reinterpret_cast<uint4*>((char*)As + boff) = p;
            } else {
                const uint4 av = *reinterpret_cast<const uint4*>(&Ab[(size_t)(m0 + row) * HID + k0 + c8]);
                *reinterpret_cast<uint4*>((char*)As + boff) = av;
            }
            const uint4 bv = *reinterpret_cast<const uint4*>(&Bt[(size_t)(n0 + row) * HID + k0 + c8]);
            *reinterpret_cast<uint4*>((char*)Bs + boff) = bv;
        }
        __syncthreads();

        const int arow = w * 16 + c;
        const int asw = (arow & 7) << 4;
        bf16x8 af0 = *reinterpret_cast<const bf16x8*>((char*)As + arow * 128 + ((g * 16) ^ asw));
        bf16x8 af1 = *reinterpret_cast<const bf16x8*>((char*)As + arow * 128 + ((64 + g * 16) ^ asw));
#pragma unroll
        for (int nq = 0; nq < 4; ++nq) {
            const int brow = nq * 16 + c;
            const int bsw = (brow & 7) << 4;
            bf16x8 bf0 = *reinterpret_cast<const bf16x8*>((char*)Bs + brow * 128 + ((g * 16) ^ bsw));
            bf16x8 bf1 = *reinterpret_cast<const bf16x8*>((char*)Bs + brow * 128 + ((64 + g * 16) ^ bsw));
            acc[nq] = __builtin_amdgcn_mfma_f32_16x16x32_bf16(af0, bf0, acc[nq], 0, 0, 0);
            acc[nq] = __builtin_amdgcn_mfma_f32_16x16x32_bf16(af1, bf1, acc[nq], 0, 0, 0);
        }
    }

#pragma unroll
    for (int nq = 0; nq < 4; ++nq) {
        const int n = n0 + nq * 16 + c;
        const float bv = HAS_BIAS ? bias[n] : 0.f;
#pragma unroll
        for (int r = 0; r < 4; ++r) {
            const int m = m0 + w * 16 + g * 4 + r;
            float v = acc[nq][r] + bv;
            if (BMODE == 0 || BMODE == 1) C[(size_t)m * ALLH + n] = v;
            if (BMODE == 1) {
                int bb = m >> 10, s = m & 1023;
                int head = n >> 6, d = n & 63;
                Chm[(((size_t)bb * HEADS + head) * SEQ + s) * 64 + d] = f2bf(v);
            }
            if (BMODE == 2) {
                int bb = m >> 10, s = m & 1023;
                int head = n >> 6, d = n & 63;
                char* tb = (char*)Chm + (((size_t)(bb * HEADS + head) * 16 + (s >> 6)) * 4096) * 2;
                unsigned off = (unsigned)(s & 63) * 128 + (((unsigned)(d * 2)) ^ ((s & 7) << 4));
                *reinterpret_cast<ushort*>(tb + off) = f2bf(v);
            }
        }
    }
}

// ---------------- fused V GEMM (1-phase): A=Vbf once, B1=WvT -> vhm V-tiles, B2=WcoT -> cob ----------------
__global__ __launch_bounds__(256) void gemm_vv(const ushort* __restrict__ A,
                                               const ushort* __restrict__ B1t,
                                               const ushort* __restrict__ B2t,
                                               const float* __restrict__ bco,
                                               ushort* __restrict__ vhm,
                                               float* __restrict__ cob) {
    __shared__ __align__(16) ushort As[64 * 64];
    __shared__ __align__(16) ushort B1s[64 * 64];
    __shared__ __align__(16) ushort B2s[64 * 64];

    const int bid = blockIdx.x;
    const int swz = (bid & 7) * 96 + (bid >> 3);
    const int n0 = (swz % 6) * 64;
    const int m0 = (swz / 6) * 64;

    const int tid = threadIdx.x;
    const int lane = tid & 63;
    const int w = tid >> 6;
    const int g = lane >> 4;
    const int c = lane & 15;

    f32x4 acc1[4] = {{0,0,0,0},{0,0,0,0},{0,0,0,0},{0,0,0,0}};
    f32x4 acc2[4] = {{0,0,0,0},{0,0,0,0},{0,0,0,0},{0,0,0,0}};

    for (int k0 = 0; k0 < HID; k0 += 64) {
        __syncthreads();
#pragma unroll
        for (int it = 0; it < 2; ++it) {
            int e = tid + it * 256;
            int row = e >> 3;
            int c8 = (e & 7) * 8;
            int boff = row * 128 + ((c8 * 2) ^ ((row & 7) << 4));
            const uint4 av = *reinterpret_cast<const uint4*>(&A[(size_t)(m0 + row) * HID + k0 + c8]);
            *reinterpret_cast<uint4*>((char*)As + boff) = av;
            const uint4 b1v = *reinterpret_cast<const uint4*>(&B1t[(size_t)(n0 + row) * HID + k0 + c8]);
            *reinterpret_cast<uint4*>((char*)B1s + boff) = b1v;
            const uint4 b2v = *reinterpret_cast<const uint4*>(&B2t[(size_t)(n0 + row) * HID + k0 + c8]);
            *reinterpret_cast<uint4*>((char*)B2s + boff) = b2v;
        }
        __syncthreads();

        const int arow = w * 16 + c;
        const int asw = (arow & 7) << 4;
        bf16x8 af0 = *reinterpret_cast<const bf16x8*>((char*)As + arow * 128 + ((g * 16) ^ asw));
        bf16x8 af1 = *reinterpret_cast<const bf16x8*>((char*)As + arow * 128 + ((64 + g * 16) ^ asw));
#pragma unroll
        for (int nq = 0; nq < 4; ++nq) {
            const int brow = nq * 16 + c;
            const int bsw = (brow & 7) << 4;
            bf16x8 v10 = *reinterpret_cast<const bf16x8*>((char*)B1s + brow * 128 + ((g * 16) ^ bsw));
            bf16x8 v11 = *reinterpret_cast<const bf16x8*>((char*)B1s + brow * 128 + ((64 + g * 16) ^ bsw));
            acc1[nq] = __builtin_amdgcn_mfma_f32_16x16x32_bf16(af0, v10, acc1[nq], 0, 0, 0);
            acc1[nq] = __builtin_amdgcn_mfma_f32_16x16x32_bf16(af1, v11, acc1[nq], 0, 0, 0);
            bf16x8 v20 = *reinterpret_cast<const bf16x8*>((char*)B2s + brow * 128 + ((g * 16) ^ bsw));
            bf16x8 v21 = *reinterpret_cast<const bf16x8*>((char*)B2s + brow * 128 + ((64 + g * 16) ^ bsw));
            acc2[nq] = __builtin_amdgcn_mfma_f32_16x16x32_bf16(af0, v20, acc2[nq], 0, 0, 0);
            acc2[nq] = __builtin_amdgcn_mfma_f32_16x16x32_bf16(af1, v21, acc2[nq], 0, 0, 0);
        }
    }

    // epilogue 1: V transposed+swizzled tiles (verbatim R10 BMODE=3)
    {
        const int head = n0 >> 6;
        const int bb = m0 >> 10;
        const int st = (m0 & 1023) >> 6;
        char* tb = (char*)vhm + (((size_t)(bb * HEADS + head) * 16 + st) * 4096) * 2;
#pragma unroll
        for (int nq = 0; nq < 4; ++nq) {
            const int d = nq * 16 + c;
            unsigned off = (unsigned)d * 128 + (((unsigned)(32 * w + 8 * g)) ^ ((d & 7) << 4));
            uint2 vv;
            vv.x = pk2(acc1[nq][0], acc1[nq][1]);
            vv.y = pk2(acc1[nq][2], acc1[nq][3]);
            *reinterpret_cast<uint2*>(tb + off) = vv;
        }
    }
    // epilogue 2: co = V@Wco + bco (f32, verbatim R10 BMODE=0)
#pragma unroll
    for (int nq = 0; nq < 4; ++nq) {
        const int n = n0 + nq * 16 + c;
        const float bv = bco[n];
#pragma unroll
        for (int r = 0; r < 4; ++r) {
            const int m = m0 + w * 16 + g * 4 + r;
            cob[(size_t)m * ALLH + n] = acc2[nq][r] + bv;
        }
    }
}

// ---------------- span kernel ----------------
__global__ __launch_bounds__(256) void spankern_kernel(const float* __restrict__ keyconv,
                                                       const float* __restrict__ q,
                                                       const float* __restrict__ Wck,
                                                       const float* __restrict__ bck,
                                                       float* __restrict__ kern_sm) {
    __shared__ float ca[4][ALLH];
    __shared__ float kv[4][64];
    int row0 = blockIdx.x * 4;
    int tid = threadIdx.x;
    int r = tid >> 6;
    int lane = tid & 63;
    int row = row0 + r;
    for (int e = lane; e < ALLH; e += 64) {
        size_t off = (size_t)row * ALLH + e;
        ca[r][e] = keyconv[off] * q[off];
    }
    __syncthreads();
    float val = 0.f;
    if (lane < HEADS * KS) {
        for (int kidx = 0; kidx < ALLH; ++kidx)
            val += ca[r][kidx] * Wck[kidx * (HEADS * KS) + lane];
        val += bck[lane];
    }
    kv[r][lane] = val;
    __syncthreads();
    if (lane < HEADS) {
        float mx = -INFINITY;
#pragma unroll
        for (int t = 0; t < KS; ++t) mx = fmaxf(mx, kv[r][lane * KS + t]);
        float e[KS];
        float sum = 0.f;
#pragma unroll
        for (int t = 0; t < KS; ++t) {
            e[t] = expf(kv[r][lane * KS + t] - mx);
            sum += e[t];
        }
        float inv = 1.f / sum;
#pragma unroll
        for (int t = 0; t < KS; ++t)
            kern_sm[((size_t)row * HEADS + lane) * KS + t] = e[t] * inv;
    }
}

// ---------------- conv_out ----------------
__global__ __launch_bounds__(256) void convout_kernel(const float* __restrict__ co,
                                                      const float* __restrict__ kern_sm,
                                                      float* __restrict__ out) {
    int idx = blockIdx.x * 256 + threadIdx.x;
    if (idx >= MROWS * (ALLH / 4)) return;
    int c4 = idx % (ALLH / 4);
    int s = (idx / (ALLH / 4)) % SEQ;
    int b = idx / ((ALLH / 4) * SEQ);
    int c = c4 * 4;
    int h = c >> 6;
    const float* ks = &kern_sm[(((size_t)b * SEQ + s) * HEADS + h) * KS];
    float kt[KS];
#pragma unroll
    for (int t = 0; t < KS; ++t) kt[t] = ks[t];
    float4 acc = {0.f, 0.f, 0.f, 0.f};
#pragma unroll
    for (int t = 0; t < KS; ++t) {
        int sj = s + t - PADC;
        if (sj >= 0 && sj < SEQ) {
            const float4 cv = *reinterpret_cast<const float4*>(&co[((size_t)b * SEQ + sj) * ALLH + c]);
            acc.x += cv.x * kt[t];
            acc.y += cv.y * kt[t];
            acc.z += cv.z * kt[t];
            acc.w += cv.w * kt[t];
        }
    }
    *reinterpret_cast<float4*>(&out[((size_t)b * SEQ + s) * (2 * ALLH) + ALLH + c]) = acc;
}

// ---------------- fused monotonic attention (MFMA, pre-swizzled tiles; verbatim R10) ----------------
__global__ __launch_bounds__(256) void attn_mfma(const ushort* __restrict__ qh,
                                                 const ushort* __restrict__ kh,
                                                 const ushort* __restrict__ vh,
                                                 const int* __restrict__ mask,
                                                 const float* __restrict__ gammas,
                                                 float* __restrict__ out) {
    __shared__ __align__(16) ushort kbuf[64 * 64];   // swizzled [key][d] tile (copied verbatim)
    __shared__ __align__(16) ushort vbuf[64 * 64];   // transposed+swizzled [d][key] tile
    __shared__ float s_msk[SEQ];

    const int bid = blockIdx.x;
    const int blk = (bid & 7) * 96 + (bid >> 3);
    const int qt = blk & 15;
    const int h = (blk >> 4) % HEADS;
    const int b = blk / (16 * HEADS);
    const int i0 = qt * 64;
    const int tid = threadIdx.x;
    const int lane = tid & 63;
    const int w = tid >> 6;
    const int g = lane >> 4;
    const int c = lane & 15;

    const float LOG2E = 1.44269504f;
    float g0 = gammas[h];
    float gamma2 = -(fmaxf(g0, 0.f) + log1pf(expf(-fabsf(g0)))) * LOG2E;  // -softplus * log2e
    const float SLOG2 = 0.125f * LOG2E;

    const ushort* ktiles = kh + ((size_t)(b * HEADS + h) * 16) * 4096;
    const ushort* vtiles = vh + ((size_t)(b * HEADS + h) * 16) * 4096;
    const ushort* qhb = qh + ((size_t)b * HEADS + h) * SEQ * 64;

    for (int e = tid; e < SEQ; e += 256)
        s_msk[e] = (mask[b * SEQ + e] != 0) ? 1.f : 0.f;

    // Q B-fragments
    bf16x8 qf0, qf1;
    {
        const ushort* qrow = qhb + (size_t)(i0 + w * 16 + c) * 64 + g * 8;
        qf0 = *reinterpret_cast<const bf16x8*>(qrow);
        qf1 = *reinterpret_cast<const bf16x8*>(qrow + 32);
    }

    // ================= pass 1: raw denominator T =================
    float Tacc = 0.f;
    for (int chk = 0; chk < 16; ++chk) {
        __syncthreads();
        const ushort* ktp = ktiles + chk * 4096;
#pragma unroll
        for (int it = 0; it < 2; ++it) {
            int e16 = (tid + it * 256) * 16;
            *reinterpret_cast<uint4*>((char*)kbuf + e16) =
                *reinterpret_cast<const uint4*>((const char*)ktp + e16);
        }
        __syncthreads();
        const int j0 = chk * 64;
#pragma unroll
        for (int m = 0; m < 4; ++m) {
            f32x4 acc = {0.f, 0.f, 0.f, 0.f};
            int row = m * 16 + c;
            int sw = (row & 7) << 4;
            bf16x8 kf0 = *reinterpret_cast<const bf16x8*>((char*)kbuf + row * 128 + ((g * 16) ^ sw));
            bf16x8 kf1 = *reinterpret_cast<const bf16x8*>((char*)kbuf + row * 128 + ((64 + g * 16) ^ sw));
            acc = __builtin_amdgcn_mfma_f32_16x16x32_bf16(kf0, qf0, acc, 0, 0, 0);
            acc = __builtin_amdgcn_mfma_f32_16x16x32_bf16(kf1, qf1, acc, 0, 0, 0);
#pragma unroll
            for (int r = 0; r < 4; ++r) {
                float mk = s_msk[j0 + m * 16 + g * 4 + r];
                Tacc += mk * fexp2(acc[r] * SLOG2);
            }
        }
    }
    Tacc += __shfl_xor(Tacc, 16, 64);
    Tacc += __shfl_xor(Tacc, 32, 64);
    const float T = Tacc;
    const float invT = (T > 0.f) ? 1.f / T : 0.f;

    // ================= pass 2: cum, effect, second softmax, PV =================
    f32x4 ctx0 = {0,0,0,0}, ctx1 = {0,0,0,0}, ctx2 = {0,0,0,0}, ctx3 = {0,0,0,0};
    float l2acc = 0.f;
    float base = 0.f;
    const float iq = (float)(i0 + w * 16 + c);
    const unsigned vx = (unsigned)((c & 7) << 4);    // lane-const read swizzle

    for (int chk = 0; chk < 16; ++chk) {
        __syncthreads();
        const ushort* ktp = ktiles + chk * 4096;
        const ushort* vtp = vtiles + chk * 4096;
#pragma unroll
        for (int it = 0; it < 2; ++it) {
            int e16 = (tid + it * 256) * 16;
            *reinterpret_cast<uint4*>((char*)kbuf + e16) =
                *reinterpret_cast<const uint4*>((const char*)ktp + e16);
            *reinterpret_cast<uint4*>((char*)vbuf + e16) =
                *reinterpret_cast<const uint4*>((const char*)vtp + e16);
        }
        __syncthreads();
        const int j0 = chk * 64;
#pragma unroll
        for (int m = 0; m < 4; ++m) {
            f32x4 acc = {0.f, 0.f, 0.f, 0.f};
            int row = m * 16 + c;
            int sw = (row & 7) << 4;
            bf16x8 kf0 = *reinterpret_cast<const bf16x8*>((char*)kbuf + row * 128 + ((g * 16) ^ sw));
            bf16x8 kf1 = *reinterpret_cast<const bf16x8*>((char*)kbuf + row * 128 + ((64 + g * 16) ^ sw));
            acc = __builtin_amdgcn_mfma_f32_16x16x32_bf16(kf0, qf0, acc, 0, 0, 0);
            acc = __builtin_amdgcn_mfma_f32_16x16x32_bf16(kf1, qf1, acc, 0, 0, 0);

            float sl[4], mk[4], incl[4];
            float li = 0.f;
#pragma unroll
            for (int r = 0; r < 4; ++r) {
                mk[r] = s_msk[j0 + m * 16 + g * 4 + r];
                sl[r] = acc[r] * SLOG2;                 // score in log2 units
                float e = mk[r] * fexp2(sl[r]);
                li += e;
                incl[r] = li;
            }
            float gs = li;
            float up = __shfl_up(gs, 16, 64); if (g >= 1) gs += up;
            up = __shfl_up(gs, 32, 64); if (g >= 2) gs += up;
            float gexcl = gs - li;
            float ttot = __shfl(gs, 48 + c, 64);

            const float dbase = iq - (float)(j0 + m * 16 + g * 4);
            float p2[4];
#pragma unroll
            for (int r = 0; r < 4; ++r) {
                float cum = base + gexcl + incl[r];
                float rem = fmaxf(1.0f - cum * invT, 0.f);
                float pos = fabsf(dbase - (float)r);
                float dist = fsqrt(rem * pos);
                float eff = fmaxf(fexp2(dist * gamma2), 1e-5f);  // gamma2<0, dist>=0 -> eff<=1
                p2[r] = mk[r] * fexp2(sl[r] * eff);
                l2acc += p2[r];
            }
            base += ttot;

            union { uint2 u; bf16x4 v; } pu;
            pu.u.x = cvtpk(p2[0], p2[1]);
            pu.u.y = cvtpk(p2[2], p2[3]);
            bf16x4 pa = pu.v;

            const unsigned cb = ((unsigned)(32 * m + 8 * g)) ^ vx;
#pragma unroll
            for (int t = 0; t < 4; ++t) {
                bf16x4 vfrag = *reinterpret_cast<const bf16x4*>((char*)vbuf + (unsigned)(c + 16 * t) * 128 + cb);
                if (t == 0) mfma16(ctx0, pa, vfrag);
                else if (t == 1) mfma16(ctx1, pa, vfrag);
                else if (t == 2) mfma16(ctx2, pa, vfrag);
                else mfma16(ctx3, pa, vfrag);
            }
        }
    }
    l2acc += __shfl_xor(l2acc, 16, 64);
    l2acc += __shfl_xor(l2acc, 32, 64);
    const float invl2 = 1.f / l2acc;

#pragma unroll
    for (int r = 0; r < 4; ++r) {
        float inv_r = __shfl(invl2, g * 4 + r, 64);
        int qrow = i0 + w * 16 + g * 4 + r;
        float* orow = out + ((size_t)b * SEQ + qrow) * (2 * ALLH) + h * DHEAD;
        orow[c +  0] = ctx0[r] * inv_r;
        orow[c + 16] = ctx1[r] * inv_r;
        orow[c + 32] = ctx2[r] * inv_r;
        orow[c + 48] = ctx3[r] * inv_r;
    }
}

// ---------------- launch ----------------
extern "C" void kernel_launch(void* const* d_in, const int* in_sizes, int n_in,
                              void* d_out, int out_size, void* d_ws, size_t ws_size,
                              hipStream_t stream) {
    const float* Q = (const float*)d_in[0];
    const float* Kin = (const float*)d_in[1];
    const float* V = (const float*)d_in[2];
    const float* Wq = (const float*)d_in[3];
    const float* Wk = (const float*)d_in[4];
    const float* Wv = (const float*)d_in[5];
    const float* dw = (const float*)d_in[6];
    const float* pw = (const float*)d_in[7];
    const float* sep_bias = (const float*)d_in[8];
    const float* Wck = (const float*)d_in[9];
    const float* bck = (const float*)d_in[10];
    const float* Wco = (const float*)d_in[11];
    const float* bco = (const float*)d_in[12];
    const float* gammas = (const float*)d_in[13];
    const int* mask = (const int*)d_in[14];
    float* out = (float*)d_out;
    float* ws = (float*)d_ws;

    const size_t NP = (size_t)MROWS * ALLH;        // 3145728
    const size_t WSZ = (size_t)ALLH * HID;         // 294912
    float* qb   = ws;                              // f32 q (spankern)
    float* cob  = qb + NP;
    float* kcb  = cob + NP;
    float* kern = kcb + NP;                        // 8192*54
    ushort* qh  = (ushort*)(kern + (size_t)MROWS * HEADS * KS);
    ushort* khm = qh + NP;                         // swizzled K tiles
    ushort* vhm = khm + NP;                        // transposed+swizzled V tiles
    ushort* Vbf = vhm + NP;                        // V bf16: MROWS*HID = 2*NP ushorts
    ushort* ybf = Vbf + 2 * NP;                    // dconv out bf16 [8192][768]
    ushort* WqT = ybf + (size_t)MROWS * HID;
    ushort* WkT = WqT + WSZ;
    ushort* WvT = WkT + WSZ;
    ushort* WcoT = WvT + WSZ;
    ushort* pwT = WcoT + WSZ;

    // 1. dtype conversions + depthwise conv
    precvt_kernel<<<MROWS * HID / (256 * 8), 256, 0, stream>>>(V, Vbf);
    dconv_kernel<<<(MROWS * (HID / 4) + 255) / 256, 256, 0, stream>>>(Kin, dw, ybf);
    wcvt_kernel<<<dim3(24, 12, 4), 256, 0, stream>>>(Wq, Wk, Wv, Wco, WqT, WkT, WvT, WcoT);
    pwcvt_kernel<<<(ALLH * HID + 255) / 256, 256, 0, stream>>>(pw, pwT);

    // 2. projection GEMMs (1-phase; Q/K convert f32 A during staging; V fused dual-B)
    gemm_mfma<1, false, true><<<768, 256, 0, stream>>>(Q, WqT, nullptr, qb, qh);
    gemm_mfma<2, false, true><<<768, 256, 0, stream>>>(Kin, WkT, nullptr, nullptr, khm);
    gemm_vv<<<768, 256, 0, stream>>>(Vbf, WvT, WcoT, bco, vhm, cob);
    gemm_mfma<0, true, false><<<768, 256, 0, stream>>>(ybf, pwT, sep_bias, kcb, nullptr);

    // 3. span-dynamic-conv kernel weights + softmax
    spankern_kernel<<<MROWS / 4, 256, 0, stream>>>(kcb, qb, Wck, bck, kern);

    // 4. conv branch output (channels 384..767)
    convout_kernel<<<(MROWS * (ALLH / 4) + 255) / 256, 256, 0, stream>>>(cob, kern, out);

    // 5. fused monotonic attention (channels 0..383)
    attn_mfma<<<BATCH * HEADS * (SEQ / 64), 256, 0, stream>>>(qh, khm, vhm, mask, gammas, out);
}

// Round 13
// 232.587 us; speedup vs baseline: 6.7610x; 1.2990x over previous
//
#include <hip/hip_runtime.h>
#include <math.h>

#define BATCH 8
#define SEQ   1024
#define HID   768
#define HEADS 6
#define DHEAD 64
#define ALLH  384   // HEADS*DHEAD
#define KS    9
#define PADC  4
#define MROWS (BATCH*SEQ)  // 8192

typedef __attribute__((ext_vector_type(8))) short bf16x8;
typedef __attribute__((ext_vector_type(4))) short bf16x4;
typedef __attribute__((ext_vector_type(4))) float f32x4;

__device__ __forceinline__ ushort f2bf(float x) {   // RTN-even f32 -> bf16 bits
    unsigned u = __float_as_uint(x);
    unsigned r = (u + 0x7FFFu + ((u >> 16) & 1u)) >> 16;
    return (ushort)r;
}
__device__ __forceinline__ unsigned pk2(float a, float b) {
    return (unsigned)f2bf(a) | ((unsigned)f2bf(b) << 16);
}
// TRANS ops via compiler-known paths (hazard handling) -- R7 lesson
__device__ __forceinline__ float fexp2(float x) {
#if __has_builtin(__builtin_amdgcn_exp2f)
    return __builtin_amdgcn_exp2f(x);
#else
    return exp2f(x);
#endif
}
__device__ __forceinline__ float fsqrt(float x) {
#if __has_builtin(__builtin_amdgcn_sqrtf)
    return __builtin_amdgcn_sqrtf(x);
#else
    return __sqrtf(x);
#endif
}
__device__ __forceinline__ unsigned cvtpk(float a, float b) {  // 2 bf16 in 1 instr (RNE, non-trans)
    unsigned r; asm("v_cvt_pk_bf16_f32 %0, %1, %2" : "=v"(r) : "v"(a), "v"(b)); return r;
}

__device__ __forceinline__ void mfma16(f32x4& c4, bf16x4 a, bf16x4 b) {
#if __has_builtin(__builtin_amdgcn_mfma_f32_16x16x16bf16_1k)
    c4 = __builtin_amdgcn_mfma_f32_16x16x16bf16_1k(a, b, c4, 0, 0, 0);
#else
    asm volatile("v_mfma_f32_16x16x16_bf16 %0, %1, %2, %0" : "+v"(c4) : "v"(a), "v"(b));
#endif
}

// ---------------- depthwise conv on K -> bf16, register sliding window ----------------
// thread: fixed (b, c4), 16 consecutive s. Each input row loaded ~1.5x (vs 9x before).
__global__ __launch_bounds__(256) void dconv_kernel(const float* __restrict__ Kin,
                                                    const float* __restrict__ dw,
                                                    ushort* __restrict__ y) {
    const int t = threadIdx.x;
    const int c4l = t & 63;         // wave = 64 consecutive c4 -> coalesced 1KB rows
    const int sg = t >> 6;          // wave-uniform
    const int c4 = blockIdx.x * 64 + c4l;   // 0..191
    const int s0 = blockIdx.y * 64 + sg * 16;
    const int b = blockIdx.z;
    const int c = c4 * 4;

    const float* base = Kin + (size_t)b * SEQ * HID + c;
    ushort* ybase = y + (size_t)b * SEQ * HID + c;

    float wv[4][KS];
#pragma unroll
    for (int j = 0; j < 4; ++j)
#pragma unroll
        for (int tt = 0; tt < KS; ++tt) wv[j][tt] = dw[(c + j) * KS + tt];

    float4 win[KS];   // win[tt] = row (s - 4 + tt)
#pragma unroll
    for (int tt = 0; tt < KS; ++tt) {
        int sj = s0 - PADC + tt;
        win[tt] = (sj >= 0 && sj < SEQ) ? *reinterpret_cast<const float4*>(base + (size_t)sj * HID)
                                        : float4{0.f, 0.f, 0.f, 0.f};
    }

#pragma unroll
    for (int i = 0; i < 16; ++i) {
        const int s = s0 + i;
        float4 acc = {0.f, 0.f, 0.f, 0.f};
#pragma unroll
        for (int tt = 0; tt < KS; ++tt) {
            acc.x += win[tt].x * wv[0][tt];
            acc.y += win[tt].y * wv[1][tt];
            acc.z += win[tt].z * wv[2][tt];
            acc.w += win[tt].w * wv[3][tt];
        }
        uint2 o;
        o.x = pk2(acc.x, acc.y); o.y = pk2(acc.z, acc.w);
        *reinterpret_cast<uint2*>(ybase + (size_t)s * HID) = o;
        // slide window: next s needs rows s+1-4 .. s+1+4
#pragma unroll
        for (int tt = 0; tt < KS - 1; ++tt) win[tt] = win[tt + 1];
        int sj = s + 1 + PADC;
        win[KS - 1] = (sj < SEQ) ? *reinterpret_cast<const float4*>(base + (size_t)sj * HID)
                                 : float4{0.f, 0.f, 0.f, 0.f};
    }
}

// ---------------- weight transpose-convert: W[768,384] f32 -> Wt[384,768] bf16 ----------------
__global__ __launch_bounds__(256) void wcvt_kernel(const float* __restrict__ W0, const float* __restrict__ W1,
                                                   const float* __restrict__ W2, const float* __restrict__ W3,
                                                   ushort* __restrict__ O0, ushort* __restrict__ O1,
                                                   ushort* __restrict__ O2, ushort* __restrict__ O3) {
    __shared__ float t[32][33];
    int wsel = blockIdx.z;
    const float* W = wsel == 0 ? W0 : wsel == 1 ? W1 : wsel == 2 ? W2 : W3;
    ushort* O = wsel == 0 ? O0 : wsel == 1 ? O1 : wsel == 2 ? O2 : O3;
    int kt = blockIdx.x * 32;
    int nt = blockIdx.y * 32;
    int tx = threadIdx.x & 31, ty = threadIdx.x >> 5;
#pragma unroll
    for (int i = 0; i < 4; ++i)
        t[ty + i * 8][tx] = W[(size_t)(kt + ty + i * 8) * ALLH + nt + tx];
    __syncthreads();
#pragma unroll
    for (int i = 0; i < 4; ++i)
        O[(size_t)(nt + ty + i * 8) * HID + kt + tx] = f2bf(t[tx][ty + i * 8]);
}

// ---------------- pw convert (already [N=384, K=768]) ----------------
__global__ __launch_bounds__(256) void pwcvt_kernel(const float* __restrict__ pw, ushort* __restrict__ pwb) {
    int i = blockIdx.x * 256 + threadIdx.x;
    if (i < ALLH * HID) pwb[i] = f2bf(pw[i]);
}

// ---------------- bf16 MFMA GEMM, 1-phase (R10-proven loop) ----------------
// C[8192,384] = A[8192,768] @ Bt[384,768]^T. AF32: A is f32, converted during staging (R6-proven).
// BMODE: 0 = f32 only, 1 = f32 + qh plain head-major, 2 = khm swizzled tiles
template <int BMODE, bool HAS_BIAS, bool AF32>
__global__ __launch_bounds__(256) void gemm_mfma(const void* __restrict__ Ap,
                                                 const ushort* __restrict__ Bt,
                                                 const float* __restrict__ bias,
                                                 float* __restrict__ C,
                                                 ushort* __restrict__ Chm) {
    __shared__ __align__(16) ushort As[64 * 64];
    __shared__ __align__(16) ushort Bs[64 * 64];

    const int bid = blockIdx.x;
    const int swz = (bid & 7) * 96 + (bid >> 3);   // bijective: 768 = 8*96
    const int n0 = (swz % 6) * 64;
    const int m0 = (swz / 6) * 64;

    const int tid = threadIdx.x;
    const int lane = tid & 63;
    const int w = tid >> 6;
    const int g = lane >> 4;
    const int c = lane & 15;

    const ushort* Ab = (const ushort*)Ap;
    const float* Af = (const float*)Ap;

    f32x4 acc[4] = {{0,0,0,0},{0,0,0,0},{0,0,0,0},{0,0,0,0}};

    for (int k0 = 0; k0 < HID; k0 += 64) {
        __syncthreads();
#pragma unroll
        for (int it = 0; it < 2; ++it) {
            int e = tid + it * 256;
            int row = e >> 3;
            int c8 = (e & 7) * 8;
            int boff = row * 128 + ((c8 * 2) ^ ((row & 7) << 4));
            if (AF32) {
                const float4 f0 = *reinterpret_cast<const float4*>(&Af[(size_t)(m0 + row) * HID + k0 + c8]);
                const float4 f1 = *reinterpret_cast<const float4*>(&Af[(size_t)(m0 + row) * HID + k0 + c8 + 4]);
                uint4 p;
                p.x = pk2(f0.x, f0.y); p.y = pk2(f0.z, f0.w);
                p.z = pk2(f1.x, f1.y); p.w = pk2(f1.z, f1.w);
                *reinterpret_cast<uint4*>((char*)As + boff) = p;
            } else {
                const uint4 av = *reinterpret_cast<const uint4*>(&Ab[(size_t)(m0 + row) * HID + k0 + c8]);
                *reinterpret_cast<uint4*>((char*)As + boff) = av;
            }
            const uint4 bv = *reinterpret_cast<const uint4*>(&Bt[(size_t)(n0 + row) * HID + k0 + c8]);
            *reinterpret_cast<uint4*>((char*)Bs + boff) = bv;
        }
        __syncthreads();

        const int arow = w * 16 + c;
        const int asw = (arow & 7) << 4;
        bf16x8 af0 = *reinterpret_cast<const bf16x8*>((char*)As + arow * 128 + ((g * 16) ^ asw));
        bf16x8 af1 = *reinterpret_cast<const bf16x8*>((char*)As + arow * 128 + ((64 + g * 16) ^ asw));
#pragma unroll
        for (int nq = 0; nq < 4; ++nq) {
            const int brow = nq * 16 + c;
            const int bsw = (brow & 7) << 4;
            bf16x8 bf0 = *reinterpret_cast<const bf16x8*>((char*)Bs + brow * 128 + ((g * 16) ^ bsw));
            bf16x8 bf1 = *reinterpret_cast<const bf16x8*>((char*)Bs + brow * 128 + ((64 + g * 16) ^ bsw));
            acc[nq] = __builtin_amdgcn_mfma_f32_16x16x32_bf16(af0, bf0, acc[nq], 0, 0, 0);
            acc[nq] = __builtin_amdgcn_mfma_f32_16x16x32_bf16(af1, bf1, acc[nq], 0, 0, 0);
        }
    }

#pragma unroll
    for (int nq = 0; nq < 4; ++nq) {
        const int n = n0 + nq * 16 + c;
        const float bv = HAS_BIAS ? bias[n] : 0.f;
#pragma unroll
        for (int r = 0; r < 4; ++r) {
            const int m = m0 + w * 16 + g * 4 + r;
            float v = acc[nq][r] + bv;
            if (BMODE == 0 || BMODE == 1) C[(size_t)m * ALLH + n] = v;
            if (BMODE == 1) {
                int bb = m >> 10, s = m & 1023;
                int head = n >> 6, d = n & 63;
                Chm[(((size_t)bb * HEADS + head) * SEQ + s) * 64 + d] = f2bf(v);
            }
            if (BMODE == 2) {
                int bb = m >> 10, s = m & 1023;
                int head = n >> 6, d = n & 63;
                char* tb = (char*)Chm + (((size_t)(bb * HEADS + head) * 16 + (s >> 6)) * 4096) * 2;
                unsigned off = (unsigned)(s & 63) * 128 + (((unsigned)(d * 2)) ^ ((s & 7) << 4));
                *reinterpret_cast<ushort*>(tb + off) = f2bf(v);
            }
        }
    }
}

// ---------------- fused V GEMM (1-phase, AF32 staging): A = f32 V, B1=WvT -> vhm tiles, B2=WcoT -> cob ----------------
__global__ __launch_bounds__(256) void gemm_vv(const float* __restrict__ Af,
                                               const ushort* __restrict__ B1t,
                                               const ushort* __restrict__ B2t,
                                               const float* __restrict__ bco,
                                               ushort* __restrict__ vhm,
                                               float* __restrict__ cob) {
    __shared__ __align__(16) ushort As[64 * 64];
    __shared__ __align__(16) ushort B1s[64 * 64];
    __shared__ __align__(16) ushort B2s[64 * 64];

    const int bid = blockIdx.x;
    const int swz = (bid & 7) * 96 + (bid >> 3);
    const int n0 = (swz % 6) * 64;
    const int m0 = (swz / 6) * 64;

    const int tid = threadIdx.x;
    const int lane = tid & 63;
    const int w = tid >> 6;
    const int g = lane >> 4;
    const int c = lane & 15;

    f32x4 acc1[4] = {{0,0,0,0},{0,0,0,0},{0,0,0,0},{0,0,0,0}};
    f32x4 acc2[4] = {{0,0,0,0},{0,0,0,0},{0,0,0,0},{0,0,0,0}};

    for (int k0 = 0; k0 < HID; k0 += 64) {
        __syncthreads();
#pragma unroll
        for (int it = 0; it < 2; ++it) {
            int e = tid + it * 256;
            int row = e >> 3;
            int c8 = (e & 7) * 8;
            int boff = row * 128 + ((c8 * 2) ^ ((row & 7) << 4));
            const float4 f0 = *reinterpret_cast<const float4*>(&Af[(size_t)(m0 + row) * HID + k0 + c8]);
            const float4 f1 = *reinterpret_cast<const float4*>(&Af[(size_t)(m0 + row) * HID + k0 + c8 + 4]);
            uint4 p;
            p.x = pk2(f0.x, f0.y); p.y = pk2(f0.z, f0.w);
            p.z = pk2(f1.x, f1.y); p.w = pk2(f1.z, f1.w);
            *reinterpret_cast<uint4*>((char*)As + boff) = p;
            const uint4 b1v = *reinterpret_cast<const uint4*>(&B1t[(size_t)(n0 + row) * HID + k0 + c8]);
            *reinterpret_cast<uint4*>((char*)B1s + boff) = b1v;
            const uint4 b2v = *reinterpret_cast<const uint4*>(&B2t[(size_t)(n0 + row) * HID + k0 + c8]);
            *reinterpret_cast<uint4*>((char*)B2s + boff) = b2v;
        }
        __syncthreads();

        const int arow = w * 16 + c;
        const int asw = (arow & 7) << 4;
        bf16x8 af0 = *reinterpret_cast<const bf16x8*>((char*)As + arow * 128 + ((g * 16) ^ asw));
        bf16x8 af1 = *reinterpret_cast<const bf16x8*>((char*)As + arow * 128 + ((64 + g * 16) ^ asw));
#pragma unroll
        for (int nq = 0; nq < 4; ++nq) {
            const int brow = nq * 16 + c;
            const int bsw = (brow & 7) << 4;
            bf16x8 v10 = *reinterpret_cast<const bf16x8*>((char*)B1s + brow * 128 + ((g * 16) ^ bsw));
            bf16x8 v11 = *reinterpret_cast<const bf16x8*>((char*)B1s + brow * 128 + ((64 + g * 16) ^ bsw));
            acc1[nq] = __builtin_amdgcn_mfma_f32_16x16x32_bf16(af0, v10, acc1[nq], 0, 0, 0);
            acc1[nq] = __builtin_amdgcn_mfma_f32_16x16x32_bf16(af1, v11, acc1[nq], 0, 0, 0);
            bf16x8 v20 = *reinterpret_cast<const bf16x8*>((char*)B2s + brow * 128 + ((g * 16) ^ bsw));
            bf16x8 v21 = *reinterpret_cast<const bf16x8*>((char*)B2s + brow * 128 + ((64 + g * 16) ^ bsw));
            acc2[nq] = __builtin_amdgcn_mfma_f32_16x16x32_bf16(af0, v20, acc2[nq], 0, 0, 0);
            acc2[nq] = __builtin_amdgcn_mfma_f32_16x16x32_bf16(af1, v21, acc2[nq], 0, 0, 0);
        }
    }

    // epilogue 1: V transposed+swizzled tiles
    {
        const int head = n0 >> 6;
        const int bb = m0 >> 10;
        const int st = (m0 & 1023) >> 6;
        char* tb = (char*)vhm + (((size_t)(bb * HEADS + head) * 16 + st) * 4096) * 2;
#pragma unroll
        for (int nq = 0; nq < 4; ++nq) {
            const int d = nq * 16 + c;
            unsigned off = (unsigned)d * 128 + (((unsigned)(32 * w + 8 * g)) ^ ((d & 7) << 4));
            uint2 vv;
            vv.x = pk2(acc1[nq][0], acc1[nq][1]);
            vv.y = pk2(acc1[nq][2], acc1[nq][3]);
            *reinterpret_cast<uint2*>(tb + off) = vv;
        }
    }
    // epilogue 2: co = V@Wco + bco (f32)
#pragma unroll
    for (int nq = 0; nq < 4; ++nq) {
        const int n = n0 + nq * 16 + c;
        const float bv = bco[n];
#pragma unroll
        for (int r = 0; r < 4; ++r) {
            const int m = m0 + w * 16 + g * 4 + r;
            cob[(size_t)m * ALLH + n] = acc2[nq][r] + bv;
        }
    }
}

// ---------------- span kernel ----------------
__global__ __launch_bounds__(256) void spankern_kernel(const float* __restrict__ keyconv,
                                                       const float* __restrict__ q,
                                                       const float* __restrict__ Wck,
                                                       const float* __restrict__ bck,
                                                       float* __restrict__ kern_sm) {
    __shared__ float ca[4][ALLH];
    __shared__ float kv[4][64];
    int row0 = blockIdx.x * 4;
    int tid = threadIdx.x;
    int r = tid >> 6;
    int lane = tid & 63;
    int row = row0 + r;
    for (int e = lane; e < ALLH; e += 64) {
        size_t off = (size_t)row * ALLH + e;
        ca[r][e] = keyconv[off] * q[off];
    }
    __syncthreads();
    float val = 0.f;
    if (lane < HEADS * KS) {
        for (int kidx = 0; kidx < ALLH; ++kidx)
            val += ca[r][kidx] * Wck[kidx * (HEADS * KS) + lane];
        val += bck[lane];
    }
    kv[r][lane] = val;
    __syncthreads();
    if (lane < HEADS) {
        float mx = -INFINITY;
#pragma unroll
        for (int t = 0; t < KS; ++t) mx = fmaxf(mx, kv[r][lane * KS + t]);
        float e[KS];
        float sum = 0.f;
#pragma unroll
        for (int t = 0; t < KS; ++t) {
            e[t] = expf(kv[r][lane * KS + t] - mx);
            sum += e[t];
        }
        float inv = 1.f / sum;
#pragma unroll
        for (int t = 0; t < KS; ++t)
            kern_sm[((size_t)row * HEADS + lane) * KS + t] = e[t] * inv;
    }
}

// ---------------- conv_out ----------------
__global__ __launch_bounds__(256) void convout_kernel(const float* __restrict__ co,
                                                      const float* __restrict__ kern_sm,
                                                      float* __restrict__ out) {
    int idx = blockIdx.x * 256 + threadIdx.x;
    if (idx >= MROWS * (ALLH / 4)) return;
    int c4 = idx % (ALLH / 4);
    int s = (idx / (ALLH / 4)) % SEQ;
    int b = idx / ((ALLH / 4) * SEQ);
    int c = c4 * 4;
    int h = c >> 6;
    const float* ks = &kern_sm[(((size_t)b * SEQ + s) * HEADS + h) * KS];
    float kt[KS];
#pragma unroll
    for (int t = 0; t < KS; ++t) kt[t] = ks[t];
    float4 acc = {0.f, 0.f, 0.f, 0.f};
#pragma unroll
    for (int t = 0; t < KS; ++t) {
        int sj = s + t - PADC;
        if (sj >= 0 && sj < SEQ) {
            const float4 cv = *reinterpret_cast<const float4*>(&co[((size_t)b * SEQ + sj) * ALLH + c]);
            acc.x += cv.x * kt[t];
            acc.y += cv.y * kt[t];
            acc.z += cv.z * kt[t];
            acc.w += cv.w * kt[t];
        }
    }
    *reinterpret_cast<float4*>(&out[((size_t)b * SEQ + s) * (2 * ALLH) + ALLH + c]) = acc;
}

// ---------------- fused monotonic attention (MFMA, pre-swizzled tiles; verbatim R10/R12) ----------------
__global__ __launch_bounds__(256) void attn_mfma(const ushort* __restrict__ qh,
                                                 const ushort* __restrict__ kh,
                                                 const ushort* __restrict__ vh,
                                                 const int* __restrict__ mask,
                                                 const float* __restrict__ gammas,
                                                 float* __restrict__ out) {
    __shared__ __align__(16) ushort kbuf[64 * 64];   // swizzled [key][d] tile (copied verbatim)
    __shared__ __align__(16) ushort vbuf[64 * 64];   // transposed+swizzled [d][key] tile
    __shared__ float s_msk[SEQ];

    const int bid = blockIdx.x;
    const int blk = (bid & 7) * 96 + (bid >> 3);
    const int qt = blk & 15;
    const int h = (blk >> 4) % HEADS;
    const int b = blk / (16 * HEADS);
    const int i0 = qt * 64;
    const int tid = threadIdx.x;
    const int lane = tid & 63;
    const int w = tid >> 6;
    const int g = lane >> 4;
    const int c = lane & 15;

    const float LOG2E = 1.44269504f;
    float g0 = gammas[h];
    float gamma2 = -(fmaxf(g0, 0.f) + log1pf(expf(-fabsf(g0)))) * LOG2E;  // -softplus * log2e
    const float SLOG2 = 0.125f * LOG2E;

    const ushort* ktiles = kh + ((size_t)(b * HEADS + h) * 16) * 4096;
    const ushort* vtiles = vh + ((size_t)(b * HEADS + h) * 16) * 4096;
    const ushort* qhb = qh + ((size_t)b * HEADS + h) * SEQ * 64;

    for (int e = tid; e < SEQ; e += 256)
        s_msk[e] = (mask[b * SEQ + e] != 0) ? 1.f : 0.f;

    // Q B-fragments
    bf16x8 qf0, qf1;
    {
        const ushort* qrow = qhb + (size_t)(i0 + w * 16 + c) * 64 + g * 8;
        qf0 = *reinterpret_cast<const bf16x8*>(qrow);
        qf1 = *reinterpret_cast<const bf16x8*>(qrow + 32);
    }

    // ================= pass 1: raw denominator T =================
    float Tacc = 0.f;
    for (int chk = 0; chk < 16; ++chk) {
        __syncthreads();
        const ushort* ktp = ktiles + chk * 4096;
#pragma unroll
        for (int it = 0; it < 2; ++it) {
            int e16 = (tid + it * 256) * 16;
            *reinterpret_cast<uint4*>((char*)kbuf + e16) =
                *reinterpret_cast<const uint4*>((const char*)ktp + e16);
        }
        __syncthreads();
        const int j0 = chk * 64;
#pragma unroll
        for (int m = 0; m < 4; ++m) {
            f32x4 acc = {0.f, 0.f, 0.f, 0.f};
            int row = m * 16 + c;
            int sw = (row & 7) << 4;
            bf16x8 kf0 = *reinterpret_cast<const bf16x8*>((char*)kbuf + row * 128 + ((g * 16) ^ sw));
            bf16x8 kf1 = *reinterpret_cast<const bf16x8*>((char*)kbuf + row * 128 + ((64 + g * 16) ^ sw));
            acc = __builtin_amdgcn_mfma_f32_16x16x32_bf16(kf0, qf0, acc, 0, 0, 0);
            acc = __builtin_amdgcn_mfma_f32_16x16x32_bf16(kf1, qf1, acc, 0, 0, 0);
#pragma unroll
            for (int r = 0; r < 4; ++r) {
                float mk = s_msk[j0 + m * 16 + g * 4 + r];
                Tacc += mk * fexp2(acc[r] * SLOG2);
            }
        }
    }
    Tacc += __shfl_xor(Tacc, 16, 64);
    Tacc += __shfl_xor(Tacc, 32, 64);
    const float T = Tacc;
    const float invT = (T > 0.f) ? 1.f / T : 0.f;

    // ================= pass 2: cum, effect, second softmax, PV =================
    f32x4 ctx0 = {0,0,0,0}, ctx1 = {0,0,0,0}, ctx2 = {0,0,0,0}, ctx3 = {0,0,0,0};
    float l2acc = 0.f;
    float base = 0.f;
    const float iq = (float)(i0 + w * 16 + c);
    const unsigned vx = (unsigned)((c & 7) << 4);    // lane-const read swizzle

    for (int chk = 0; chk < 16; ++chk) {
        __syncthreads();
        const ushort* ktp = ktiles + chk * 4096;
        const ushort* vtp = vtiles + chk * 4096;
#pragma unroll
        for (int it = 0; it < 2; ++it) {
            int e16 = (tid + it * 256) * 16;
            *reinterpret_cast<uint4*>((char*)kbuf + e16) =
                *reinterpret_cast<const uint4*>((const char*)ktp + e16);
            *reinterpret_cast<uint4*>((char*)vbuf + e16) =
                *reinterpret_cast<const uint4*>((const char*)vtp + e16);
        }
        __syncthreads();
        const int j0 = chk * 64;
#pragma unroll
        for (int m = 0; m < 4; ++m) {
            f32x4 acc = {0.f, 0.f, 0.f, 0.f};
            int row = m * 16 + c;
            int sw = (row & 7) << 4;
            bf16x8 kf0 = *reinterpret_cast<const bf16x8*>((char*)kbuf + row * 128 + ((g * 16) ^ sw));
            bf16x8 kf1 = *reinterpret_cast<const bf16x8*>((char*)kbuf + row * 128 + ((64 + g * 16) ^ sw));
            acc = __builtin_amdgcn_mfma_f32_16x16x32_bf16(kf0, qf0, acc, 0, 0, 0);
            acc = __builtin_amdgcn_mfma_f32_16x16x32_bf16(kf1, qf1, acc, 0, 0, 0);

            float sl[4], mk[4], incl[4];
            float li = 0.f;
#pragma unroll
            for (int r = 0; r < 4; ++r) {
                mk[r] = s_msk[j0 + m * 16 + g * 4 + r];
                sl[r] = acc[r] * SLOG2;                 // score in log2 units
                float e = mk[r] * fexp2(sl[r]);
                li += e;
                incl[r] = li;
            }
            float gs = li;
            float up = __shfl_up(gs, 16, 64); if (g >= 1) gs += up;
            up = __shfl_up(gs, 32, 64); if (g >= 2) gs += up;
            float gexcl = gs - li;
            float ttot = __shfl(gs, 48 + c, 64);

            const float dbase = iq - (float)(j0 + m * 16 + g * 4);
            float p2[4];
#pragma unroll
            for (int r = 0; r < 4; ++r) {
                float cum = base + gexcl + incl[r];
                float rem = fmaxf(1.0f - cum * invT, 0.f);
                float pos = fabsf(dbase - (float)r);
                float dist = fsqrt(rem * pos);
                float eff = fmaxf(fexp2(dist * gamma2), 1e-5f);  // gamma2<0, dist>=0 -> eff<=1
                p2[r] = mk[r] * fexp2(sl[r] * eff);
                l2acc += p2[r];
            }
            base += ttot;

            union { uint2 u; bf16x4 v; } pu;
            pu.u.x = cvtpk(p2[0], p2[1]);
            pu.u.y = cvtpk(p2[2], p2[3]);
            bf16x4 pa = pu.v;

            const unsigned cb = ((unsigned)(32 * m + 8 * g)) ^ vx;
#pragma unroll
            for (int t = 0; t < 4; ++t) {
                bf16x4 vfrag = *reinterpret_cast<const bf16x4*>((char*)vbuf + (unsigned)(c + 16 * t) * 128 + cb);
                if (t == 0) mfma16(ctx0, pa, vfrag);
                else if (t == 1) mfma16(ctx1, pa, vfrag);
                else if (t == 2) mfma16(ctx2, pa, vfrag);
                else mfma16(ctx3, pa, vfrag);
            }
        }
    }
    l2acc += __shfl_xor(l2acc, 16, 64);
    l2acc += __shfl_xor(l2acc, 32, 64);
    const float invl2 = 1.f / l2acc;

#pragma unroll
    for (int r = 0; r < 4; ++r) {
        float inv_r = __shfl(invl2, g * 4 + r, 64);
        int qrow = i0 + w * 16 + g * 4 + r;
        float* orow = out + ((size_t)b * SEQ + qrow) * (2 * ALLH) + h * DHEAD;
        orow[c +  0] = ctx0[r] * inv_r;
        orow[c + 16] = ctx1[r] * inv_r;
        orow[c + 32] = ctx2[r] * inv_r;
        orow[c + 48] = ctx3[r] * inv_r;
    }
}

// ---------------- launch ----------------
extern "C" void kernel_launch(void* const* d_in, const int* in_sizes, int n_in,
                              void* d_out, int out_size, void* d_ws, size_t ws_size,
                              hipStream_t stream) {
    const float* Q = (const float*)d_in[0];
    const float* Kin = (const float*)d_in[1];
    const float* V = (const float*)d_in[2];
    const float* Wq = (const float*)d_in[3];
    const float* Wk = (const float*)d_in[4];
    const float* Wv = (const float*)d_in[5];
    const float* dw = (const float*)d_in[6];
    const float* pw = (const float*)d_in[7];
    const float* sep_bias = (const float*)d_in[8];
    const float* Wck = (const float*)d_in[9];
    const float* bck = (const float*)d_in[10];
    const float* Wco = (const float*)d_in[11];
    const float* bco = (const float*)d_in[12];
    const float* gammas = (const float*)d_in[13];
    const int* mask = (const int*)d_in[14];
    float* out = (float*)d_out;
    float* ws = (float*)d_ws;

    const size_t NP = (size_t)MROWS * ALLH;        // 3145728
    const size_t WSZ = (size_t)ALLH * HID;         // 294912
    float* qb   = ws;                              // f32 q (spankern)
    float* cob  = qb + NP;
    float* kcb  = cob + NP;
    float* kern = kcb + NP;                        // 8192*54
    ushort* qh  = (ushort*)(kern + (size_t)MROWS * HEADS * KS);
    ushort* khm = qh + NP;                         // swizzled K tiles
    ushort* vhm = khm + NP;                        // transposed+swizzled V tiles
    ushort* ybf = vhm + NP;                        // dconv out bf16 [8192][768]
    ushort* WqT = ybf + (size_t)MROWS * HID;
    ushort* WkT = WqT + WSZ;
    ushort* WvT = WkT + WSZ;
    ushort* WcoT = WvT + WSZ;
    ushort* pwT = WcoT + WSZ;

    // 1. depthwise conv (register sliding window) + weight conversions
    dconv_kernel<<<dim3(3, 16, BATCH), 256, 0, stream>>>(Kin, dw, ybf);
    wcvt_kernel<<<dim3(24, 12, 4), 256, 0, stream>>>(Wq, Wk, Wv, Wco, WqT, WkT, WvT, WcoT);
    pwcvt_kernel<<<(ALLH * HID + 255) / 256, 256, 0, stream>>>(pw, pwT);

    // 2. projection GEMMs (1-phase; f32 A converted during staging; V fused dual-B)
    gemm_mfma<1, false, true><<<768, 256, 0, stream>>>(Q, WqT, nullptr, qb, qh);
    gemm_mfma<2, false, true><<<768, 256, 0, stream>>>(Kin, WkT, nullptr, nullptr, khm);
    gemm_vv<<<768, 256, 0, stream>>>(V, WvT, WcoT, bco, vhm, cob);
    gemm_mfma<0, true, false><<<768, 256, 0, stream>>>(ybf, pwT, sep_bias, kcb, nullptr);

    // 3. span-dynamic-conv kernel weights + softmax
    spankern_kernel<<<MROWS / 4, 256, 0, stream>>>(kcb, qb, Wck, bck, kern);

    // 4. conv branch output (channels 384..767)
    convout_kernel<<<(MROWS * (ALLH / 4) + 255) / 256, 256, 0, stream>>>(cob, kern, out);

    // 5. fused monotonic attention (channels 0..383)
    attn_mfma<<<BATCH * HEADS * (SEQ / 64), 256, 0, stream>>>(qh, khm, vhm, mask, gammas, out);
}

// Round 14
// 226.436 us; speedup vs baseline: 6.9447x; 1.0272x over previous
//
#include <hip/hip_runtime.h>
#include <math.h>

#define BATCH 8
#define SEQ   1024
#define HID   768
#define HEADS 6
#define DHEAD 64
#define ALLH  384   // HEADS*DHEAD
#define KS    9
#define PADC  4
#define MROWS (BATCH*SEQ)  // 8192

typedef __attribute__((ext_vector_type(8))) short bf16x8;
typedef __attribute__((ext_vector_type(4))) short bf16x4;
typedef __attribute__((ext_vector_type(4))) float f32x4;

__device__ __forceinline__ ushort f2bf(float x) {   // RTN-even f32 -> bf16 bits
    unsigned u = __float_as_uint(x);
    unsigned r = (u + 0x7FFFu + ((u >> 16) & 1u)) >> 16;
    return (ushort)r;
}
__device__ __forceinline__ unsigned pk2(float a, float b) {
    return (unsigned)f2bf(a) | ((unsigned)f2bf(b) << 16);
}
// TRANS ops via compiler-known paths (hazard handling) -- R7 lesson
__device__ __forceinline__ float fexp2(float x) {
#if __has_builtin(__builtin_amdgcn_exp2f)
    return __builtin_amdgcn_exp2f(x);
#else
    return exp2f(x);
#endif
}
__device__ __forceinline__ float fsqrt(float x) {
#if __has_builtin(__builtin_amdgcn_sqrtf)
    return __builtin_amdgcn_sqrtf(x);
#else
    return __sqrtf(x);
#endif
}
__device__ __forceinline__ unsigned cvtpk(float a, float b) {  // 2 bf16 in 1 instr (RNE, non-trans)
    unsigned r; asm("v_cvt_pk_bf16_f32 %0, %1, %2" : "=v"(r) : "v"(a), "v"(b)); return r;
}

__device__ __forceinline__ void mfma16(f32x4& c4, bf16x4 a, bf16x4 b) {
#if __has_builtin(__builtin_amdgcn_mfma_f32_16x16x16bf16_1k)
    c4 = __builtin_amdgcn_mfma_f32_16x16x16bf16_1k(a, b, c4, 0, 0, 0);
#else
    asm volatile("v_mfma_f32_16x16x16_bf16 %0, %1, %2, %0" : "+v"(c4) : "v"(a), "v"(b));
#endif
}

// ---------------- depthwise conv on K -> bf16, register sliding window ----------------
__global__ __launch_bounds__(256) void dconv_kernel(const float* __restrict__ Kin,
                                                    const float* __restrict__ dw,
                                                    ushort* __restrict__ y) {
    const int t = threadIdx.x;
    const int c4l = t & 63;
    const int sg = t >> 6;
    const int c4 = blockIdx.x * 64 + c4l;
    const int s0 = blockIdx.y * 64 + sg * 16;
    const int b = blockIdx.z;
    const int c = c4 * 4;

    const float* base = Kin + (size_t)b * SEQ * HID + c;
    ushort* ybase = y + (size_t)b * SEQ * HID + c;

    float wv[4][KS];
#pragma unroll
    for (int j = 0; j < 4; ++j)
#pragma unroll
        for (int tt = 0; tt < KS; ++tt) wv[j][tt] = dw[(c + j) * KS + tt];

    float4 win[KS];
#pragma unroll
    for (int tt = 0; tt < KS; ++tt) {
        int sj = s0 - PADC + tt;
        win[tt] = (sj >= 0 && sj < SEQ) ? *reinterpret_cast<const float4*>(base + (size_t)sj * HID)
                                        : float4{0.f, 0.f, 0.f, 0.f};
    }

#pragma unroll
    for (int i = 0; i < 16; ++i) {
        const int s = s0 + i;
        float4 acc = {0.f, 0.f, 0.f, 0.f};
#pragma unroll
        for (int tt = 0; tt < KS; ++tt) {
            acc.x += win[tt].x * wv[0][tt];
            acc.y += win[tt].y * wv[1][tt];
            acc.z += win[tt].z * wv[2][tt];
            acc.w += win[tt].w * wv[3][tt];
        }
        uint2 o;
        o.x = pk2(acc.x, acc.y); o.y = pk2(acc.z, acc.w);
        *reinterpret_cast<uint2*>(ybase + (size_t)s * HID) = o;
#pragma unroll
        for (int tt = 0; tt < KS - 1; ++tt) win[tt] = win[tt + 1];
        int sj = s + 1 + PADC;
        win[KS - 1] = (sj < SEQ) ? *reinterpret_cast<const float4*>(base + (size_t)sj * HID)
                                 : float4{0.f, 0.f, 0.f, 0.f};
    }
}

// ---------------- weight transpose-convert: W[768,384] f32 -> Wt[384,768] bf16 ----------------
__global__ __launch_bounds__(256) void wcvt_kernel(const float* __restrict__ W0, const float* __restrict__ W1,
                                                   const float* __restrict__ W2, const float* __restrict__ W3,
                                                   ushort* __restrict__ O0, ushort* __restrict__ O1,
                                                   ushort* __restrict__ O2, ushort* __restrict__ O3) {
    __shared__ float t[32][33];
    int wsel = blockIdx.z;
    const float* W = wsel == 0 ? W0 : wsel == 1 ? W1 : wsel == 2 ? W2 : W3;
    ushort* O = wsel == 0 ? O0 : wsel == 1 ? O1 : wsel == 2 ? O2 : O3;
    int kt = blockIdx.x * 32;
    int nt = blockIdx.y * 32;
    int tx = threadIdx.x & 31, ty = threadIdx.x >> 5;
#pragma unroll
    for (int i = 0; i < 4; ++i)
        t[ty + i * 8][tx] = W[(size_t)(kt + ty + i * 8) * ALLH + nt + tx];
    __syncthreads();
#pragma unroll
    for (int i = 0; i < 4; ++i)
        O[(size_t)(nt + ty + i * 8) * HID + kt + tx] = f2bf(t[tx][ty + i * 8]);
}

// ---------------- pw convert (already [N=384, K=768]) ----------------
__global__ __launch_bounds__(256) void pwcvt_kernel(const float* __restrict__ pw, ushort* __restrict__ pwb) {
    int i = blockIdx.x * 256 + threadIdx.x;
    if (i < ALLH * HID) pwb[i] = f2bf(pw[i]);
}

// ---------------- merged projection GEMMs, 128x128 tiles, 1-phase ----------------
// 5 units x 192 blocks = 960. unit: 0=Q->qb+qh, 1=K->khm tiles, 2=V@Wv->vhm tiles,
// 3=V@Wco->cob(+bco), 4=ybf@pw->kcb(+sep_bias). Wave w -> 64x64 quadrant (wr=w>>1, wc=w&1).
__global__ __launch_bounds__(256) void gemm_all(const float* __restrict__ Q,
                                                const float* __restrict__ Kin,
                                                const float* __restrict__ V,
                                                const ushort* __restrict__ ybf,
                                                const ushort* __restrict__ WqT,
                                                const ushort* __restrict__ WkT,
                                                const ushort* __restrict__ WvT,
                                                const ushort* __restrict__ WcoT,
                                                const ushort* __restrict__ pwT,
                                                const float* __restrict__ bco,
                                                const float* __restrict__ sep_bias,
                                                float* __restrict__ qb,
                                                ushort* __restrict__ qh,
                                                ushort* __restrict__ khm,
                                                ushort* __restrict__ vhm,
                                                float* __restrict__ cob,
                                                float* __restrict__ kcb) {
    __shared__ __align__(16) ushort As[128 * 64];
    __shared__ __align__(16) ushort Bs[128 * 64];

    const int bx = blockIdx.x;
    const int swz = (bx & 7) * 120 + (bx >> 3);   // bijective: 960 = 8*120
    const int unit = swz / 192;
    const int local = swz % 192;
    const int n0 = (local % 3) * 128;
    const int m0 = (local / 3) * 128;

    const float* Af = unit == 0 ? Q : unit == 1 ? Kin : V;   // units 0..3 f32
    const ushort* Ab = ybf;                                   // unit 4 bf16
    const ushort* Bt = unit == 0 ? WqT : unit == 1 ? WkT : unit == 2 ? WvT : unit == 3 ? WcoT : pwT;
    const bool af32 = (unit != 4);

    const int tid = threadIdx.x;
    const int lane = tid & 63;
    const int w = tid >> 6;
    const int wr = w >> 1, wc = w & 1;
    const int g = lane >> 4;
    const int c = lane & 15;

    f32x4 acc[4][4];
#pragma unroll
    for (int i = 0; i < 4; ++i)
#pragma unroll
        for (int j = 0; j < 4; ++j) acc[i][j] = f32x4{0.f, 0.f, 0.f, 0.f};

    for (int k0 = 0; k0 < HID; k0 += 64) {
        __syncthreads();
#pragma unroll
        for (int it = 0; it < 4; ++it) {
            int e = tid + it * 256;            // 0..1023
            int row = e >> 3;                  // 0..127
            int c8 = (e & 7) * 8;
            int boff = row * 128 + ((c8 * 2) ^ ((row & 7) << 4));
            if (af32) {
                const float4 f0 = *reinterpret_cast<const float4*>(&Af[(size_t)(m0 + row) * HID + k0 + c8]);
                const float4 f1 = *reinterpret_cast<const float4*>(&Af[(size_t)(m0 + row) * HID + k0 + c8 + 4]);
                uint4 p;
                p.x = pk2(f0.x, f0.y); p.y = pk2(f0.z, f0.w);
                p.z = pk2(f1.x, f1.y); p.w = pk2(f1.z, f1.w);
                *reinterpret_cast<uint4*>((char*)As + boff) = p;
            } else {
                const uint4 av = *reinterpret_cast<const uint4*>(&Ab[(size_t)(m0 + row) * HID + k0 + c8]);
                *reinterpret_cast<uint4*>((char*)As + boff) = av;
            }
            const uint4 bv = *reinterpret_cast<const uint4*>(&Bt[(size_t)(n0 + row) * HID + k0 + c8]);
            *reinterpret_cast<uint4*>((char*)Bs + boff) = bv;
        }
        __syncthreads();

        bf16x8 af0[4], af1[4];
#pragma unroll
        for (int mq = 0; mq < 4; ++mq) {
            const int arow = wr * 64 + mq * 16 + c;
            const int asw = (arow & 7) << 4;
            af0[mq] = *reinterpret_cast<const bf16x8*>((char*)As + arow * 128 + ((g * 16) ^ asw));
            af1[mq] = *reinterpret_cast<const bf16x8*>((char*)As + arow * 128 + ((64 + g * 16) ^ asw));
        }
#pragma unroll
        for (int nq = 0; nq < 4; ++nq) {
            const int brow = wc * 64 + nq * 16 + c;
            const int bsw = (brow & 7) << 4;
            bf16x8 bf0 = *reinterpret_cast<const bf16x8*>((char*)Bs + brow * 128 + ((g * 16) ^ bsw));
            bf16x8 bf1 = *reinterpret_cast<const bf16x8*>((char*)Bs + brow * 128 + ((64 + g * 16) ^ bsw));
#pragma unroll
            for (int mq = 0; mq < 4; ++mq) {
                acc[mq][nq] = __builtin_amdgcn_mfma_f32_16x16x32_bf16(af0[mq], bf0, acc[mq][nq], 0, 0, 0);
                acc[mq][nq] = __builtin_amdgcn_mfma_f32_16x16x32_bf16(af1[mq], bf1, acc[mq][nq], 0, 0, 0);
            }
        }
    }

    // ---------------- epilogues ----------------
    if (unit == 2) {
        // V@Wv -> transposed+swizzled 64x64 tiles [d-row][key-col]
#pragma unroll
        for (int mq = 0; mq < 4; ++mq) {
            const int mbase = m0 + wr * 64 + mq * 16 + g * 4;   // key of acc[mq][nq][0]
            const int bb = mbase >> 10;
            const int st = (mbase & 1023) >> 6;
            const unsigned colb = (unsigned)(32 * mq + 8 * g);  // 2*(key&63) base
#pragma unroll
            for (int nq = 0; nq < 4; ++nq) {
                const int n = n0 + wc * 64 + nq * 16 + c;
                const int head = n >> 6;
                const int d = n & 63;
                char* tb = (char*)vhm + (((size_t)(bb * HEADS + head) * 16 + st) * 4096) * 2;
                unsigned off = (unsigned)d * 128 + (colb ^ ((d & 7) << 4));
                uint2 vv;
                vv.x = pk2(acc[mq][nq][0], acc[mq][nq][1]);
                vv.y = pk2(acc[mq][nq][2], acc[mq][nq][3]);
                *reinterpret_cast<uint2*>(tb + off) = vv;
            }
        }
        return;
    }

#pragma unroll
    for (int nq = 0; nq < 4; ++nq) {
        const int n = n0 + wc * 64 + nq * 16 + c;
        float bv = 0.f;
        if (unit == 3) bv = bco[n];
        if (unit == 4) bv = sep_bias[n];
#pragma unroll
        for (int mq = 0; mq < 4; ++mq) {
#pragma unroll
            for (int r = 0; r < 4; ++r) {
                const int m = m0 + wr * 64 + mq * 16 + g * 4 + r;
                float v = acc[mq][nq][r] + bv;
                if (unit == 0) {
                    qb[(size_t)m * ALLH + n] = v;
                    int bb = m >> 10, s = m & 1023;
                    int head = n >> 6, d = n & 63;
                    qh[(((size_t)bb * HEADS + head) * SEQ + s) * 64 + d] = f2bf(v);
                } else if (unit == 1) {
                    int bb = m >> 10, s = m & 1023;
                    int head = n >> 6, d = n & 63;
                    char* tb = (char*)khm + (((size_t)(bb * HEADS + head) * 16 + (s >> 6)) * 4096) * 2;
                    unsigned off = (unsigned)(s & 63) * 128 + (((unsigned)(d * 2)) ^ ((s & 7) << 4));
                    *reinterpret_cast<ushort*>(tb + off) = f2bf(v);
                } else if (unit == 3) {
                    cob[(size_t)m * ALLH + n] = v;
                } else {  // unit 4
                    kcb[(size_t)m * ALLH + n] = v;
                }
            }
        }
    }
}

// ---------------- span kernel ----------------
__global__ __launch_bounds__(256) void spankern_kernel(const float* __restrict__ keyconv,
                                                       const float* __restrict__ q,
                                                       const float* __restrict__ Wck,
                                                       const float* __restrict__ bck,
                                                       float* __restrict__ kern_sm) {
    __shared__ float ca[4][ALLH];
    __shared__ float kv[4][64];
    int row0 = blockIdx.x * 4;
    int tid = threadIdx.x;
    int r = tid >> 6;
    int lane = tid & 63;
    int row = row0 + r;
    for (int e = lane; e < ALLH; e += 64) {
        size_t off = (size_t)row * ALLH + e;
        ca[r][e] = keyconv[off] * q[off];
    }
    __syncthreads();
    float val = 0.f;
    if (lane < HEADS * KS) {
        for (int kidx = 0; kidx < ALLH; ++kidx)
            val += ca[r][kidx] * Wck[kidx * (HEADS * KS) + lane];
        val += bck[lane];
    }
    kv[r][lane] = val;
    __syncthreads();
    if (lane < HEADS) {
        float mx = -INFINITY;
#pragma unroll
        for (int t = 0; t < KS; ++t) mx = fmaxf(mx, kv[r][lane * KS + t]);
        float e[KS];
        float sum = 0.f;
#pragma unroll
        for (int t = 0; t < KS; ++t) {
            e[t] = expf(kv[r][lane * KS + t] - mx);
            sum += e[t];
        }
        float inv = 1.f / sum;
#pragma unroll
        for (int t = 0; t < KS; ++t)
            kern_sm[((size_t)row * HEADS + lane) * KS + t] = e[t] * inv;
    }
}

// ---------------- conv_out ----------------
__global__ __launch_bounds__(256) void convout_kernel(const float* __restrict__ co,
                                                      const float* __restrict__ kern_sm,
                                                      float* __restrict__ out) {
    int idx = blockIdx.x * 256 + threadIdx.x;
    if (idx >= MROWS * (ALLH / 4)) return;
    int c4 = idx % (ALLH / 4);
    int s = (idx / (ALLH / 4)) % SEQ;
    int b = idx / ((ALLH / 4) * SEQ);
    int c = c4 * 4;
    int h = c >> 6;
    const float* ks = &kern_sm[(((size_t)b * SEQ + s) * HEADS + h) * KS];
    float kt[KS];
#pragma unroll
    for (int t = 0; t < KS; ++t) kt[t] = ks[t];
    float4 acc = {0.f, 0.f, 0.f, 0.f};
#pragma unroll
    for (int t = 0; t < KS; ++t) {
        int sj = s + t - PADC;
        if (sj >= 0 && sj < SEQ) {
            const float4 cv = *reinterpret_cast<const float4*>(&co[((size_t)b * SEQ + sj) * ALLH + c]);
            acc.x += cv.x * kt[t];
            acc.y += cv.y * kt[t];
            acc.z += cv.z * kt[t];
            acc.w += cv.w * kt[t];
        }
    }
    *reinterpret_cast<float4*>(&out[((size_t)b * SEQ + s) * (2 * ALLH) + ALLH + c]) = acc;
}

// ---------------- fused monotonic attention (MFMA, pre-swizzled tiles; verbatim R10/R12/R13) ----------------
__global__ __launch_bounds__(256) void attn_mfma(const ushort* __restrict__ qh,
                                                 const ushort* __restrict__ kh,
                                                 const ushort* __restrict__ vh,
                                                 const int* __restrict__ mask,
                                                 const float* __restrict__ gammas,
                                                 float* __restrict__ out) {
    __shared__ __align__(16) ushort kbuf[64 * 64];   // swizzled [key][d] tile (copied verbatim)
    __shared__ __align__(16) ushort vbuf[64 * 64];   // transposed+swizzled [d][key] tile
    __shared__ float s_msk[SEQ];

    const int bid = blockIdx.x;
    const int blk = (bid & 7) * 96 + (bid >> 3);
    const int qt = blk & 15;
    const int h = (blk >> 4) % HEADS;
    const int b = blk / (16 * HEADS);
    const int i0 = qt * 64;
    const int tid = threadIdx.x;
    const int lane = tid & 63;
    const int w = tid >> 6;
    const int g = lane >> 4;
    const int c = lane & 15;

    const float LOG2E = 1.44269504f;
    float g0 = gammas[h];
    float gamma2 = -(fmaxf(g0, 0.f) + log1pf(expf(-fabsf(g0)))) * LOG2E;  // -softplus * log2e
    const float SLOG2 = 0.125f * LOG2E;

    const ushort* ktiles = kh + ((size_t)(b * HEADS + h) * 16) * 4096;
    const ushort* vtiles = vh + ((size_t)(b * HEADS + h) * 16) * 4096;
    const ushort* qhb = qh + ((size_t)b * HEADS + h) * SEQ * 64;

    for (int e = tid; e < SEQ; e += 256)
        s_msk[e] = (mask[b * SEQ + e] != 0) ? 1.f : 0.f;

    // Q B-fragments
    bf16x8 qf0, qf1;
    {
        const ushort* qrow = qhb + (size_t)(i0 + w * 16 + c) * 64 + g * 8;
        qf0 = *reinterpret_cast<const bf16x8*>(qrow);
        qf1 = *reinterpret_cast<const bf16x8*>(qrow + 32);
    }

    // ================= pass 1: raw denominator T =================
    float Tacc = 0.f;
    for (int chk = 0; chk < 16; ++chk) {
        __syncthreads();
        const ushort* ktp = ktiles + chk * 4096;
#pragma unroll
        for (int it = 0; it < 2; ++it) {
            int e16 = (tid + it * 256) * 16;
            *reinterpret_cast<uint4*>((char*)kbuf + e16) =
                *reinterpret_cast<const uint4*>((const char*)ktp + e16);
        }
        __syncthreads();
        const int j0 = chk * 64;
#pragma unroll
        for (int m = 0; m < 4; ++m) {
            f32x4 acc = {0.f, 0.f, 0.f, 0.f};
            int row = m * 16 + c;
            int sw = (row & 7) << 4;
            bf16x8 kf0 = *reinterpret_cast<const bf16x8*>((char*)kbuf + row * 128 + ((g * 16) ^ sw));
            bf16x8 kf1 = *reinterpret_cast<const bf16x8*>((char*)kbuf + row * 128 + ((64 + g * 16) ^ sw));
            acc = __builtin_amdgcn_mfma_f32_16x16x32_bf16(kf0, qf0, acc, 0, 0, 0);
            acc = __builtin_amdgcn_mfma_f32_16x16x32_bf16(kf1, qf1, acc, 0, 0, 0);
#pragma unroll
            for (int r = 0; r < 4; ++r) {
                float mk = s_msk[j0 + m * 16 + g * 4 + r];
                Tacc += mk * fexp2(acc[r] * SLOG2);
            }
        }
    }
    Tacc += __shfl_xor(Tacc, 16, 64);
    Tacc += __shfl_xor(Tacc, 32, 64);
    const float T = Tacc;
    const float invT = (T > 0.f) ? 1.f / T : 0.f;

    // ================= pass 2: cum, effect, second softmax, PV =================
    f32x4 ctx0 = {0,0,0,0}, ctx1 = {0,0,0,0}, ctx2 = {0,0,0,0}, ctx3 = {0,0,0,0};
    float l2acc = 0.f;
    float base = 0.f;
    const float iq = (float)(i0 + w * 16 + c);
    const unsigned vx = (unsigned)((c & 7) << 4);    // lane-const read swizzle

    for (int chk = 0; chk < 16; ++chk) {
        __syncthreads();
        const ushort* ktp = ktiles + chk * 4096;
        const ushort* vtp = vtiles + chk * 4096;
#pragma unroll
        for (int it = 0; it < 2; ++it) {
            int e16 = (tid + it * 256) * 16;
            *reinterpret_cast<uint4*>((char*)kbuf + e16) =
                *reinterpret_cast<const uint4*>((const char*)ktp + e16);
            *reinterpret_cast<uint4*>((char*)vbuf + e16) =
                *reinterpret_cast<const uint4*>((const char*)vtp + e16);
        }
        __syncthreads();
        const int j0 = chk * 64;
#pragma unroll
        for (int m = 0; m < 4; ++m) {
            f32x4 acc = {0.f, 0.f, 0.f, 0.f};
            int row = m * 16 + c;
            int sw = (row & 7) << 4;
            bf16x8 kf0 = *reinterpret_cast<const bf16x8*>((char*)kbuf + row * 128 + ((g * 16) ^ sw));
            bf16x8 kf1 = *reinterpret_cast<const bf16x8*>((char*)kbuf + row * 128 + ((64 + g * 16) ^ sw));
            acc = __builtin_amdgcn_mfma_f32_16x16x32_bf16(kf0, qf0, acc, 0, 0, 0);
            acc = __builtin_amdgcn_mfma_f32_16x16x32_bf16(kf1, qf1, acc, 0, 0, 0);

            float sl[4], mk[4], incl[4];
            float li = 0.f;
#pragma unroll
            for (int r = 0; r < 4; ++r) {
                mk[r] = s_msk[j0 + m * 16 + g * 4 + r];
                sl[r] = acc[r] * SLOG2;                 // score in log2 units
                float e = mk[r] * fexp2(sl[r]);
                li += e;
                incl[r] = li;
            }
            float gs = li;
            float up = __shfl_up(gs, 16, 64); if (g >= 1) gs += up;
            up = __shfl_up(gs, 32, 64); if (g >= 2) gs += up;
            float gexcl = gs - li;
            float ttot = __shfl(gs, 48 + c, 64);

            const float dbase = iq - (float)(j0 + m * 16 + g * 4);
            float p2[4];
#pragma unroll
            for (int r = 0; r < 4; ++r) {
                float cum = base + gexcl + incl[r];
                float rem = fmaxf(1.0f - cum * invT, 0.f);
                float pos = fabsf(dbase - (float)r);
                float dist = fsqrt(rem * pos);
                float eff = fmaxf(fexp2(dist * gamma2), 1e-5f);  // gamma2<0, dist>=0 -> eff<=1
                p2[r] = mk[r] * fexp2(sl[r] * eff);
                l2acc += p2[r];
            }
            base += ttot;

            union { uint2 u; bf16x4 v; } pu;
            pu.u.x = cvtpk(p2[0], p2[1]);
            pu.u.y = cvtpk(p2[2], p2[3]);
            bf16x4 pa = pu.v;

            const unsigned cb = ((unsigned)(32 * m + 8 * g)) ^ vx;
#pragma unroll
            for (int t = 0; t < 4; ++t) {
                bf16x4 vfrag = *reinterpret_cast<const bf16x4*>((char*)vbuf + (unsigned)(c + 16 * t) * 128 + cb);
                if (t == 0) mfma16(ctx0, pa, vfrag);
                else if (t == 1) mfma16(ctx1, pa, vfrag);
                else if (t == 2) mfma16(ctx2, pa, vfrag);
                else mfma16(ctx3, pa, vfrag);
            }
        }
    }
    l2acc += __shfl_xor(l2acc, 16, 64);
    l2acc += __shfl_xor(l2acc, 32, 64);
    const float invl2 = 1.f / l2acc;

#pragma unroll
    for (int r = 0; r < 4; ++r) {
        float inv_r = __shfl(invl2, g * 4 + r, 64);
        int qrow = i0 + w * 16 + g * 4 + r;
        float* orow = out + ((size_t)b * SEQ + qrow) * (2 * ALLH) + h * DHEAD;
        orow[c +  0] = ctx0[r] * inv_r;
        orow[c + 16] = ctx1[r] * inv_r;
        orow[c + 32] = ctx2[r] * inv_r;
        orow[c + 48] = ctx3[r] * inv_r;
    }
}

// ---------------- launch ----------------
extern "C" void kernel_launch(void* const* d_in, const int* in_sizes, int n_in,
                              void* d_out, int out_size, void* d_ws, size_t ws_size,
                              hipStream_t stream) {
    const float* Q = (const float*)d_in[0];
    const float* Kin = (const float*)d_in[1];
    const float* V = (const float*)d_in[2];
    const float* Wq = (const float*)d_in[3];
    const float* Wk = (const float*)d_in[4];
    const float* Wv = (const float*)d_in[5];
    const float* dw = (const float*)d_in[6];
    const float* pw = (const float*)d_in[7];
    const float* sep_bias = (const float*)d_in[8];
    const float* Wck = (const float*)d_in[9];
    const float* bck = (const float*)d_in[10];
    const float* Wco = (const float*)d_in[11];
    const float* bco = (const float*)d_in[12];
    const float* gammas = (const float*)d_in[13];
    const int* mask = (const int*)d_in[14];
    float* out = (float*)d_out;
    float* ws = (float*)d_ws;

    const size_t NP = (size_t)MROWS * ALLH;        // 3145728
    const size_t WSZ = (size_t)ALLH * HID;         // 294912
    float* qb   = ws;                              // f32 q (spankern)
    float* cob  = qb + NP;
    float* kcb  = cob + NP;
    float* kern = kcb + NP;                        // 8192*54
    ushort* qh  = (ushort*)(kern + (size_t)MROWS * HEADS * KS);
    ushort* khm = qh + NP;                         // swizzled K tiles
    ushort* vhm = khm + NP;                        // transposed+swizzled V tiles
    ushort* ybf = vhm + NP;                        // dconv out bf16 [8192][768]
    ushort* WqT = ybf + (size_t)MROWS * HID;
    ushort* WkT = WqT + WSZ;
    ushort* WvT = WkT + WSZ;
    ushort* WcoT = WvT + WSZ;
    ushort* pwT = WcoT + WSZ;

    // 1. depthwise conv (register sliding window) + weight conversions
    dconv_kernel<<<dim3(3, 16, BATCH), 256, 0, stream>>>(Kin, dw, ybf);
    wcvt_kernel<<<dim3(24, 12, 4), 256, 0, stream>>>(Wq, Wk, Wv, Wco, WqT, WkT, WvT, WcoT);
    pwcvt_kernel<<<(ALLH * HID + 255) / 256, 256, 0, stream>>>(pw, pwT);

    // 2. all five projection GEMMs in one 128x128-tile dispatch
    gemm_all<<<960, 256, 0, stream>>>(Q, Kin, V, ybf, WqT, WkT, WvT, WcoT, pwT,
                                      bco, sep_bias, qb, qh, khm, vhm, cob, kcb);

    // 3. span-dynamic-conv kernel weights + softmax
    spankern_kernel<<<MROWS / 4, 256, 0, stream>>>(kcb, qb, Wck, bck, kern);

    // 4. conv branch output (channels 384..767)
    convout_kernel<<<(MROWS * (ALLH / 4) + 255) / 256, 256, 0, stream>>>(cob, kern, out);

    // 5. fused monotonic attention (channels 0..383)
    attn_mfma<<<BATCH * HEADS * (SEQ / 64), 256, 0, stream>>>(qh, khm, vhm, mask, gammas, out);
}